// Round 1
// 800.204 us; speedup vs baseline: 1.0075x; 1.0075x over previous
//
#include <hip/hip_runtime.h>
#include <cstdint>
#include <cstddef>

#define N_NODES 100000
#define N_EDGES 3200000
#define IN_FEAT 512
#define HIDDEN  256
#define N_CLASS 40
#define S2_STRIDE 48         // support2 rows padded 40 -> 48 bf16 (96 B)

#define N_BUCKETS 196        // ceil(100000 / 512), bucket = row >> 9
#define SC_CHUNK 4096        // edges per binscatter block (256 thr x 16)
#define N_SC_BLOCKS 782      // ceil(3.2e6 / 4096)

// ---------------------------------------------------------------------------
// Workspace layout (bytes), 256B-aligned
//   support1 : N_NODES*HIDDEN bf16 (row-major) = 51,200,000
//   h        : N_NODES*HIDDEN bf16  =  51,200,000
//   support2 : N_NODES*48 bf16      =   9,600,000
//   w1t      : HIDDEN x IN_FEAT bf16 =    262,144
//   w2t      : 48 x HIDDEN bf16      =     24,576 -> 24,832 pad
//   rptr     : (N_NODES+1) i32      ->     400,128
//   bcnt/bbase/bcur : ~196 i32 each ->       1,024 each
//   binned   : N_EDGES int2         =  25,600,000
//   sedge    : N_EDGES int2         =  25,600,000
// ---------------------------------------------------------------------------
#define OFF_SUPPORT1 ((size_t)0)
#define OFF_H        ((size_t)51200000)
#define OFF_SUPPORT2 ((size_t)102400000)
#define OFF_W1T      ((size_t)112000000)
#define OFF_W2T      ((size_t)112262144)
#define OFF_RPTR     ((size_t)112286976)
#define OFF_BCNT     ((size_t)112687104)
#define OFF_BBASE    ((size_t)112688128)
#define OFF_BCUR     ((size_t)112689152)
#define OFF_BINNED   ((size_t)112690176)
#define OFF_SEDGE    ((size_t)138290176)

typedef __attribute__((ext_vector_type(8))) short short8x;
typedef __attribute__((ext_vector_type(4))) float f32x4;
typedef __attribute__((ext_vector_type(8))) unsigned short u16x8;
typedef __attribute__((ext_vector_type(3))) unsigned int u32x3;
typedef __attribute__((ext_vector_type(4))) unsigned int u32x4;

static __device__ __forceinline__ unsigned short f2bf(float f) {
  unsigned u = __float_as_uint(f);
  unsigned r = (u + 0x7FFFu + ((u >> 16) & 1u)) >> 16;  // RNE
  return (unsigned short)r;
}
static __device__ __forceinline__ float bf2f(unsigned short s) {
  return __uint_as_float(((unsigned)s) << 16);
}
static __device__ __forceinline__ float bflo(unsigned u) {
  return __uint_as_float(u << 16);
}
static __device__ __forceinline__ float bfhi(unsigned u) {
  return __uint_as_float(u & 0xFFFF0000u);
}

// async global->LDS, 16B per lane, dest = wave-uniform base + lane*16
static __device__ __forceinline__ void gl16(const void* g, void* l) {
  __builtin_amdgcn_global_load_lds(
      (const __attribute__((address_space(1))) unsigned int*)g,
      (__attribute__((address_space(3))) unsigned int*)l, 16, 0, 0);
}

// ------- bucket histogram + W1/W2 transpose/cast (merged, spare threads) ----
// grid 512 x 256 = 131072 threads: covers w1t (131072 elems) and w2t (12288)
__global__ __launch_bounds__(256) void k_bincnt(const int* __restrict__ erow,
                                                int* __restrict__ bcnt,
                                                const float* __restrict__ W1,
                                                unsigned short* __restrict__ W1t,
                                                const float* __restrict__ W2,
                                                unsigned short* __restrict__ W2t) {
  int tid = blockIdx.x * 256 + threadIdx.x;
  {
    int n = tid & 255;
    int k = tid >> 8;
    W1t[(size_t)n * IN_FEAT + k] = f2bf(W1[(size_t)k * HIDDEN + n]);
  }
  if (tid < 48 * HIDDEN) {
    int n = tid >> 8;          // 0..47
    int k = tid & 255;         // 0..255
    W2t[n * HIDDEN + k] = (n < N_CLASS) ? f2bf(W2[(size_t)k * N_CLASS + n]) : 0;
  }
  __shared__ int lh[256];
  lh[threadIdx.x] = 0;
  __syncthreads();
  int i = tid;
  int stride = gridDim.x * blockDim.x;
  for (; i < N_EDGES; i += stride) atomicAdd(&lh[erow[i] >> 9], 1);
  __syncthreads();
  if (threadIdx.x < N_BUCKETS) atomicAdd(&bcnt[threadIdx.x], lh[threadIdx.x]);
}

__global__ __launch_bounds__(256) void k_binscan(const int* __restrict__ bcnt,
                                                 int* __restrict__ bbase,
                                                 int* __restrict__ bcur,
                                                 int* __restrict__ rptr) {
  __shared__ int s[256];
  int t = threadIdx.x;
  int v = (t < N_BUCKETS) ? bcnt[t] : 0;
  s[t] = v;
  __syncthreads();
  for (int off = 1; off < 256; off <<= 1) {
    int y = (t >= off) ? s[t - off] : 0;
    __syncthreads();
    s[t] += y;
    __syncthreads();
  }
  if (t < N_BUCKETS) {
    int e = s[t] - v;
    bbase[t] = e;
    bcur[t] = e;
  }
  if (t == 0) {
    bbase[N_BUCKETS] = N_EDGES;
    rptr[N_NODES] = N_EDGES;
  }
}

__global__ __launch_bounds__(256) void k_binscatter(const int* __restrict__ erow,
                                                    const int* __restrict__ ecol,
                                                    const float* __restrict__ eval,
                                                    int* __restrict__ bcur,
                                                    int2* __restrict__ binned) {
  __shared__ int lcnt[256];
  __shared__ int lcur[256];
  const int t = threadIdx.x;
  const int base = blockIdx.x * SC_CHUNK;
  lcnt[t] = 0;
  __syncthreads();
  int rows[16], cols[16], vals[16];
#pragma unroll
  for (int e = 0; e < 16; e++) {
    int i = base + t + e * 256;
    if (i < N_EDGES) {
      rows[e] = erow[i];
      cols[e] = ecol[i];
      vals[e] = __float_as_int(eval[i]);
      atomicAdd(&lcnt[rows[e] >> 9], 1);
    } else {
      rows[e] = -1;
    }
  }
  __syncthreads();
  if (t < N_BUCKETS) lcur[t] = atomicAdd(&bcur[t], lcnt[t]);
  __syncthreads();
#pragma unroll
  for (int e = 0; e < 16; e++) {
    if (rows[e] >= 0) {
      int bkt = rows[e] >> 9;
      int p = atomicAdd(&lcur[bkt], 1);
      binned[p] = make_int2(((rows[e] & 511) << 17) | cols[e], vals[e]);
    }
  }
}

__global__ __launch_bounds__(256) void k_bucket_csr(const int2* __restrict__ binned,
                                                    const int* __restrict__ bbase,
                                                    int* __restrict__ rptr,
                                                    int2* __restrict__ sedge) {
  const int b = blockIdx.x;
  const int t = threadIdx.x;
  __shared__ int cnt[512];
  __shared__ int excl[512];
  __shared__ int s[256];
  cnt[t] = 0;
  cnt[t + 256] = 0;
  __syncthreads();
  const int ebase = bbase[b];
  const int ecnt = bbase[b + 1] - ebase;
  for (int i = t; i < ecnt; i += 256)
    atomicAdd(&cnt[((unsigned)binned[ebase + i].x) >> 17], 1);
  __syncthreads();
  int c0 = cnt[2 * t], c1 = cnt[2 * t + 1];
  s[t] = c0 + c1;
  __syncthreads();
  for (int off = 1; off < 256; off <<= 1) {
    int y = (t >= off) ? s[t - off] : 0;
    __syncthreads();
    s[t] += y;
    __syncthreads();
  }
  int e = s[t] - (c0 + c1);
  excl[2 * t] = e;
  excl[2 * t + 1] = e + c0;
  __syncthreads();
  for (int i = t; i < 512; i += 256) {
    int node = b * 512 + i;
    if (node < N_NODES) rptr[node] = ebase + excl[i];
  }
  __syncthreads();
  for (int i = t; i < ecnt; i += 256) {
    int2 e2 = binned[ebase + i];
    int lrow = ((unsigned)e2.x) >> 17;
    int col = e2.x & 0x1FFFF;
    int p = atomicAdd(&excl[lrow], 1);
    sedge[ebase + p] = make_int2(col, e2.y);
  }
}

// ------------- GEMM1 (MFMA): support1 = bf16(X @ W1), row-major out ---------
// M=100000, N=256 (full width per block -> X read ONCE), K=512.
// 128x256 block tile, 4 waves each 64x128 (4x8 fragments), BK=32.
// v2: m97 structure — A staged fp32 + B staged bf16 via global_load_lds
// (width 16), single-buffer 2-barrier loop, 16B-chunk XOR swizzle applied on
// the GLOBAL source address (gload_lds dest must stay linear) and undone on
// the ds_read side. f2bf conversion moved to the consume side (overlaps MFMA).
__global__ __launch_bounds__(256) void k_gemm1(const float* __restrict__ X,
                                               const unsigned short* __restrict__ Wt,
                                               unsigned short* __restrict__ C) {
  __shared__ float AsF[128 * 32];           // 16 KB fp32 [row][32], chunk-swizzled
  __shared__ unsigned short BsS[256 * 32];  // 16 KB bf16 [row][32], chunk-swizzled
  const int t = threadIdx.x;
  const int wave = t >> 6, lane = t & 63;
  const int q = lane >> 4, r = lane & 15;
  const int wm = (wave >> 1) * 64;   // 0 or 64
  const int wn = (wave & 1) * 128;   // 0 or 128
  const int m0 = blockIdx.x * 128;

  // staging geometry (k0-invariant): each wave round writes 1 KB linear LDS.
  // A: row = j*32 + wave*8 + (lane>>3), chunk(16B)= lane&7, swz: gc = c ^ (row&7)
  // B: row = j*64 + wave*16 + (lane>>2), chunk    = lane&3, swz: gc = c ^ (row&3)
  const int ar_base = wave * 8 + (lane >> 3);
  const int ac = lane & 7;
  const int br_base = wave * 16 + (lane >> 2);
  const int bc = lane & 3;

  f32x4 acc[4][8];
#pragma unroll
  for (int mi = 0; mi < 4; mi++)
#pragma unroll
    for (int ni = 0; ni < 8; ni++) acc[mi][ni] = (f32x4){0.f, 0.f, 0.f, 0.f};

  for (int k0 = 0; k0 < IN_FEAT; k0 += 32) {
#pragma unroll
    for (int j = 0; j < 4; j++) {
      int row = ar_base + j * 32;
      int gr = m0 + row;
      if (gr > N_NODES - 1) gr = N_NODES - 1;
      int gc = ac ^ (row & 7);
      gl16(&X[(size_t)gr * IN_FEAT + k0 + gc * 4],
           (char*)AsF + j * 4096 + wave * 1024);
    }
#pragma unroll
    for (int j = 0; j < 4; j++) {
      int row = br_base + j * 64;
      int gc = bc ^ (row & 3);
      gl16(&Wt[(size_t)row * IN_FEAT + k0 + gc * 8],
           (char*)BsS + j * 4096 + wave * 1024);
    }
    __syncthreads();   // drains vmcnt: tiles resident

    short8x af[4];
#pragma unroll
    for (int mi = 0; mi < 4; mi++) {
      int row = wm + mi * 16 + r;
      int sw = row & 7;
      const float* Ar = &AsF[row * 32];
      f32x4 a0 = *(const f32x4*)&Ar[(((q << 1)) ^ sw) << 2];
      f32x4 a1 = *(const f32x4*)&Ar[(((q << 1) | 1) ^ sw) << 2];
      short8x a;
      a[0] = (short)f2bf(a0[0]); a[1] = (short)f2bf(a0[1]);
      a[2] = (short)f2bf(a0[2]); a[3] = (short)f2bf(a0[3]);
      a[4] = (short)f2bf(a1[0]); a[5] = (short)f2bf(a1[1]);
      a[6] = (short)f2bf(a1[2]); a[7] = (short)f2bf(a1[3]);
      af[mi] = a;
    }
#pragma unroll
    for (int ni = 0; ni < 8; ni++) {
      int row = wn + ni * 16 + r;
      short8x b = *(const short8x*)&BsS[row * 32 + ((q ^ (row & 3)) << 3)];
#pragma unroll
      for (int mi = 0; mi < 4; mi++)
        acc[mi][ni] = __builtin_amdgcn_mfma_f32_16x16x32_bf16(af[mi], b,
                                                              acc[mi][ni], 0, 0, 0);
    }
    __syncthreads();   // tile fully consumed before next overwrite
  }
#pragma unroll
  for (int mi = 0; mi < 4; mi++) {
#pragma unroll
    for (int ni = 0; ni < 8; ni++) {
      int col = wn + ni * 16 + r;
#pragma unroll
      for (int reg = 0; reg < 4; reg++) {
        int row = m0 + wm + mi * 16 + q * 4 + reg;
        if (row < N_NODES)
          C[(size_t)row * HIDDEN + col] = f2bf(acc[mi][ni][reg]);
      }
    }
  }
}

// ---------------- SpMM1: h = bf16(relu(A @ support1 + b1)) ------------------
// one wave per node; 2 edge-slots x 32 lanes x ushort8 (16 B) per row.
// launched as TWO half-grids (diagnostic: expose other kernels in top-5)
__global__ __launch_bounds__(256) void k_spmm1(const unsigned short* __restrict__ S,
                                               const int* __restrict__ rptr,
                                               const int2* __restrict__ sedge,
                                               const float* __restrict__ b1,
                                               unsigned short* __restrict__ H,
                                               int node_off) {
  const int node = node_off + ((blockIdx.x * blockDim.x + threadIdx.x) >> 6);
  const int lane = threadIdx.x & 63;
  const int half = lane >> 5;   // edge slot 0/1
  const int fl = lane & 31;     // feature group: feats fl*8 .. fl*8+7
  int e0 = rptr[node], e1 = rptr[node + 1];
  float a[8];
#pragma unroll
  for (int k = 0; k < 8; k++) a[k] = 0.f;
  for (int base = e0; base < e1; base += 64) {
    int rem = min(64, e1 - base);
    int c = 0;
    float v = 0.f;
    if (lane < rem) {
      int2 e = sedge[base + lane];
      c = e.x;
      v = __int_as_float(e.y);
    }
    int iters = (rem + 1) >> 1;
#pragma unroll 8
    for (int j = 0; j < iters; j++) {
      int idx = 2 * j + half;            // inactive tail: c=0,v=0 -> adds 0
      int cj = __shfl(c, idx);
      float vj = __shfl(v, idx);
      short8x s8 = *(const short8x*)&S[(size_t)cj * HIDDEN + fl * 8];
#pragma unroll
      for (int k = 0; k < 8; k++)
        a[k] += vj * bf2f((unsigned short)s8[k]);
    }
  }
#pragma unroll
  for (int k = 0; k < 8; k++) a[k] += __shfl_xor(a[k], 32);
  if (half == 0) {
    float4 b0 = *(const float4*)&b1[fl * 8];
    float4 b4 = *(const float4*)&b1[fl * 8 + 4];
    u16x8 o;
    o[0] = f2bf(fmaxf(a[0] + b0.x, 0.f));
    o[1] = f2bf(fmaxf(a[1] + b0.y, 0.f));
    o[2] = f2bf(fmaxf(a[2] + b0.z, 0.f));
    o[3] = f2bf(fmaxf(a[3] + b0.w, 0.f));
    o[4] = f2bf(fmaxf(a[4] + b4.x, 0.f));
    o[5] = f2bf(fmaxf(a[5] + b4.y, 0.f));
    o[6] = f2bf(fmaxf(a[6] + b4.z, 0.f));
    o[7] = f2bf(fmaxf(a[7] + b4.w, 0.f));
    *(u16x8*)&H[(size_t)node * HIDDEN + fl * 8] = o;
  }
}

// ------- GEMM2 (MFMA): support2 = bf16(H @ W2t^T), 48-col, K=256 ------------
// grid = ceil(100000/64), block 256 = 4 waves; wave = 16 rows x 48 cols.
// A,B frags loaded straight from global (H bf16, W2t bf16 L2-resident).
__global__ __launch_bounds__(256) void k_gemm2(const unsigned short* __restrict__ H,
                                               const unsigned short* __restrict__ W2t,
                                               unsigned short* __restrict__ S2) {
  const int t = threadIdx.x;
  const int wave = t >> 6, lane = t & 63;
  const int q = lane >> 4, r = lane & 15;
  const int m0 = blockIdx.x * 64 + wave * 16;

  f32x4 acc[3];
#pragma unroll
  for (int n = 0; n < 3; n++) acc[n] = (f32x4){0.f, 0.f, 0.f, 0.f};

  int arow = m0 + r;
  if (arow > N_NODES - 1) arow = N_NODES - 1;
  const unsigned short* Arow = &H[(size_t)arow * HIDDEN + q * 8];

#pragma unroll
  for (int k0 = 0; k0 < HIDDEN; k0 += 32) {
    short8x af = *(const short8x*)&Arow[k0];
    short8x bf0 = *(const short8x*)&W2t[(0 * 16 + r) * HIDDEN + k0 + q * 8];
    short8x bf1 = *(const short8x*)&W2t[(1 * 16 + r) * HIDDEN + k0 + q * 8];
    short8x bf2 = *(const short8x*)&W2t[(2 * 16 + r) * HIDDEN + k0 + q * 8];
    acc[0] = __builtin_amdgcn_mfma_f32_16x16x32_bf16(af, bf0, acc[0], 0, 0, 0);
    acc[1] = __builtin_amdgcn_mfma_f32_16x16x32_bf16(af, bf1, acc[1], 0, 0, 0);
    acc[2] = __builtin_amdgcn_mfma_f32_16x16x32_bf16(af, bf2, acc[2], 0, 0, 0);
  }
  // C layout: col = r, row = q*4+reg
#pragma unroll
  for (int n = 0; n < 3; n++) {
#pragma unroll
    for (int reg = 0; reg < 4; reg++) {
      int row = m0 + q * 4 + reg;
      if (row < N_NODES)
        S2[(size_t)row * S2_STRIDE + n * 16 + r] = f2bf(acc[n][reg]);
    }
  }
}

// --- SpMM2 + bias + log_softmax: 8 edge-slots x 8 lanes x 6 bf16 (12 B) -----
__global__ __launch_bounds__(256) void k_spmm2(const unsigned short* __restrict__ S2,
                                               const int* __restrict__ rptr,
                                               const int2* __restrict__ sedge,
                                               const float* __restrict__ b2,
                                               float* __restrict__ out) {
  const int node = (blockIdx.x * blockDim.x + threadIdx.x) >> 6;
  const int lane = threadIdx.x & 63;
  const int q = lane >> 3;    // edge slot 0..7
  const int fl = lane & 7;    // feats fl*6 .. fl*6+5 (covers 0..47 incl pad)
  int e0 = rptr[node], e1 = rptr[node + 1];
  float a[6] = {0.f, 0.f, 0.f, 0.f, 0.f, 0.f};
  for (int base = e0; base < e1; base += 64) {
    int rem = min(64, e1 - base);
    int c = 0;
    float v = 0.f;
    if (lane < rem) {
      int2 e = sedge[base + lane];
      c = e.x;
      v = __int_as_float(e.y);
    }
    int iters = (rem + 7) >> 3;
#pragma unroll 8
    for (int j = 0; j < iters; j++) {
      int idx = 8 * j + q;               // inactive tail: c=0,v=0 -> adds 0
      int cj = __shfl(c, idx);
      float vj = __shfl(v, idx);
      u32x3 w = *(const u32x3*)&S2[(size_t)cj * S2_STRIDE + fl * 6];
      a[0] += vj * bflo(w.x);
      a[1] += vj * bfhi(w.x);
      a[2] += vj * bflo(w.y);
      a[3] += vj * bfhi(w.y);
      a[4] += vj * bflo(w.z);
      a[5] += vj * bfhi(w.z);
    }
  }
#pragma unroll
  for (int k = 0; k < 6; k++) {
    a[k] += __shfl_xor(a[k], 8);
    a[k] += __shfl_xor(a[k], 16);
    a[k] += __shfl_xor(a[k], 32);
  }
  float x[6];
  float mloc = -INFINITY;
#pragma unroll
  for (int k = 0; k < 6; k++) {
    int f = fl * 6 + k;
    x[k] = (f < N_CLASS) ? (a[k] + b2[f]) : -INFINITY;
    mloc = fmaxf(mloc, x[k]);
  }
#pragma unroll
  for (int o = 1; o < 8; o <<= 1) mloc = fmaxf(mloc, __shfl_xor(mloc, o));
  float sloc = 0.f;
#pragma unroll
  for (int k = 0; k < 6; k++)
    sloc += (fl * 6 + k < N_CLASS) ? expf(x[k] - mloc) : 0.f;
#pragma unroll
  for (int o = 1; o < 8; o <<= 1) sloc += __shfl_xor(sloc, o);
  float ls = logf(sloc);
  if (q == 0) {
#pragma unroll
    for (int k = 0; k < 6; k++) {
      int f = fl * 6 + k;
      if (f < N_CLASS) out[(size_t)node * N_CLASS + f] = (x[k] - mloc) - ls;
    }
  }
}

// ---------------------------------------------------------------------------
extern "C" void kernel_launch(void* const* d_in, const int* in_sizes, int n_in,
                              void* d_out, int out_size, void* d_ws, size_t ws_size,
                              hipStream_t stream) {
  const float* x    = (const float*)d_in[0];
  const float* w1   = (const float*)d_in[1];
  const float* b1   = (const float*)d_in[2];
  const float* w2   = (const float*)d_in[3];
  const float* b2   = (const float*)d_in[4];
  const float* eval = (const float*)d_in[5];
  const int*   erow = (const int*)d_in[6];
  const int*   ecol = (const int*)d_in[7];
  float* out = (float*)d_out;

  char* ws = (char*)d_ws;
  unsigned short* support1 = (unsigned short*)(ws + OFF_SUPPORT1);
  unsigned short* h        = (unsigned short*)(ws + OFF_H);
  unsigned short* support2 = (unsigned short*)(ws + OFF_SUPPORT2);
  unsigned short* w1t = (unsigned short*)(ws + OFF_W1T);
  unsigned short* w2t = (unsigned short*)(ws + OFF_W2T);
  int*   rptr   = (int*)(ws + OFF_RPTR);
  int*   bcnt   = (int*)(ws + OFF_BCNT);
  int*   bbase  = (int*)(ws + OFF_BBASE);
  int*   bcur   = (int*)(ws + OFF_BCUR);
  int2*  binned = (int2*)(ws + OFF_BINNED);
  int2*  sedge  = (int2*)(ws + OFF_SEDGE);

  // ---- CSR build (bucketed) + weight prep ----
  hipMemsetAsync(bcnt, 0, N_BUCKETS * 4, stream);
  k_bincnt<<<512, 256, 0, stream>>>(erow, bcnt, w1, w1t, w2, w2t);
  k_binscan<<<1, 256, 0, stream>>>(bcnt, bbase, bcur, rptr);
  k_binscatter<<<N_SC_BLOCKS, 256, 0, stream>>>(erow, ecol, eval, bcur, binned);
  k_bucket_csr<<<N_BUCKETS, 256, 0, stream>>>(binned, bbase, rptr, sedge);

  // ---- layer 1 ----
  k_gemm1<<<dim3((N_NODES + 127) / 128, 1), 256, 0, stream>>>(x, w1t, support1);
  k_spmm1<<<N_NODES / 8, 256, 0, stream>>>(support1, rptr, sedge, b1, h, 0);
  k_spmm1<<<N_NODES / 8, 256, 0, stream>>>(support1, rptr, sedge, b1, h, N_NODES / 2);

  // ---- layer 2 ----
  k_gemm2<<<(N_NODES + 63) / 64, 256, 0, stream>>>(h, w2t, support2);
  k_spmm2<<<N_NODES / 4, 256, 0, stream>>>(support2, rptr, sedge, b2, out);
}

// Round 2
// 797.714 us; speedup vs baseline: 1.0106x; 1.0031x over previous
//
#include <hip/hip_runtime.h>
#include <cstdint>
#include <cstddef>

#define N_NODES 100000
#define N_EDGES 3200000
#define IN_FEAT 512
#define HIDDEN  256
#define N_CLASS 40
#define S2_STRIDE 48         // support2 rows padded 40 -> 48 bf16 (96 B)

#define N_BUCKETS 196        // ceil(100000 / 512), bucket = row >> 9
#define SC_CHUNK 4096        // edges per binscatter block (256 thr x 16)
#define N_SC_BLOCKS 782      // ceil(3.2e6 / 4096)

// ---------------------------------------------------------------------------
// Workspace layout (bytes), 256B-aligned
// ---------------------------------------------------------------------------
#define OFF_SUPPORT1 ((size_t)0)
#define OFF_H        ((size_t)51200000)
#define OFF_SUPPORT2 ((size_t)102400000)
#define OFF_W1T      ((size_t)112000000)
#define OFF_W2T      ((size_t)112262144)
#define OFF_RPTR     ((size_t)112286976)
#define OFF_BCNT     ((size_t)112687104)
#define OFF_BBASE    ((size_t)112688128)
#define OFF_BCUR     ((size_t)112689152)
#define OFF_BINNED   ((size_t)112690176)
#define OFF_SEDGE    ((size_t)138290176)

typedef __attribute__((ext_vector_type(8))) short short8x;
typedef __attribute__((ext_vector_type(4))) float f32x4;
typedef __attribute__((ext_vector_type(8))) unsigned short u16x8;
typedef __attribute__((ext_vector_type(3))) unsigned int u32x3;
typedef __attribute__((ext_vector_type(4))) unsigned int u32x4;

static __device__ __forceinline__ unsigned short f2bf(float f) {
  unsigned u = __float_as_uint(f);
  unsigned r = (u + 0x7FFFu + ((u >> 16) & 1u)) >> 16;  // RNE
  return (unsigned short)r;
}
static __device__ __forceinline__ float bf2f(unsigned short s) {
  return __uint_as_float(((unsigned)s) << 16);
}
static __device__ __forceinline__ float bflo(unsigned u) {
  return __uint_as_float(u << 16);
}
static __device__ __forceinline__ float bfhi(unsigned u) {
  return __uint_as_float(u & 0xFFFF0000u);
}

// async global->LDS, 16B per lane, dest = wave-uniform base + lane*16
static __device__ __forceinline__ void gl16(const void* g, void* l) {
  __builtin_amdgcn_global_load_lds(
      (const __attribute__((address_space(1))) unsigned int*)g,
      (__attribute__((address_space(3))) unsigned int*)l, 16, 0, 0);
}

// ------- bucket histogram + W1/W2 transpose/cast (merged, spare threads) ----
// grid 512 x 256 = 131072 threads: covers w1t (131072 elems) and w2t (12288)
__global__ __launch_bounds__(256) void k_bincnt(const int* __restrict__ erow,
                                                int* __restrict__ bcnt,
                                                const float* __restrict__ W1,
                                                unsigned short* __restrict__ W1t,
                                                const float* __restrict__ W2,
                                                unsigned short* __restrict__ W2t) {
  int tid = blockIdx.x * 256 + threadIdx.x;
  {
    int n = tid & 255;
    int k = tid >> 8;
    W1t[(size_t)n * IN_FEAT + k] = f2bf(W1[(size_t)k * HIDDEN + n]);
  }
  if (tid < 48 * HIDDEN) {
    int n = tid >> 8;          // 0..47
    int k = tid & 255;         // 0..255
    W2t[n * HIDDEN + k] = (n < N_CLASS) ? f2bf(W2[(size_t)k * N_CLASS + n]) : 0;
  }
  __shared__ int lh[256];
  lh[threadIdx.x] = 0;
  __syncthreads();
  int i = tid;
  int stride = gridDim.x * blockDim.x;
  for (; i < N_EDGES; i += stride) atomicAdd(&lh[erow[i] >> 9], 1);
  __syncthreads();
  if (threadIdx.x < N_BUCKETS) atomicAdd(&bcnt[threadIdx.x], lh[threadIdx.x]);
}

__global__ __launch_bounds__(256) void k_binscan(const int* __restrict__ bcnt,
                                                 int* __restrict__ bbase,
                                                 int* __restrict__ bcur,
                                                 int* __restrict__ rptr) {
  __shared__ int s[256];
  int t = threadIdx.x;
  int v = (t < N_BUCKETS) ? bcnt[t] : 0;
  s[t] = v;
  __syncthreads();
  for (int off = 1; off < 256; off <<= 1) {
    int y = (t >= off) ? s[t - off] : 0;
    __syncthreads();
    s[t] += y;
    __syncthreads();
  }
  if (t < N_BUCKETS) {
    int e = s[t] - v;
    bbase[t] = e;
    bcur[t] = e;
  }
  if (t == 0) {
    bbase[N_BUCKETS] = N_EDGES;
    rptr[N_NODES] = N_EDGES;
  }
}

__global__ __launch_bounds__(256) void k_binscatter(const int* __restrict__ erow,
                                                    const int* __restrict__ ecol,
                                                    const float* __restrict__ eval,
                                                    int* __restrict__ bcur,
                                                    int2* __restrict__ binned) {
  __shared__ int lcnt[256];
  __shared__ int lcur[256];
  const int t = threadIdx.x;
  const int base = blockIdx.x * SC_CHUNK;
  lcnt[t] = 0;
  __syncthreads();
  int rows[16], cols[16], vals[16];
#pragma unroll
  for (int e = 0; e < 16; e++) {
    int i = base + t + e * 256;
    if (i < N_EDGES) {
      rows[e] = erow[i];
      cols[e] = ecol[i];
      vals[e] = __float_as_int(eval[i]);
      atomicAdd(&lcnt[rows[e] >> 9], 1);
    } else {
      rows[e] = -1;
    }
  }
  __syncthreads();
  if (t < N_BUCKETS) lcur[t] = atomicAdd(&bcur[t], lcnt[t]);
  __syncthreads();
#pragma unroll
  for (int e = 0; e < 16; e++) {
    if (rows[e] >= 0) {
      int bkt = rows[e] >> 9;
      int p = atomicAdd(&lcur[bkt], 1);
      binned[p] = make_int2(((rows[e] & 511) << 17) | cols[e], vals[e]);
    }
  }
}

__global__ __launch_bounds__(256) void k_bucket_csr(const int2* __restrict__ binned,
                                                    const int* __restrict__ bbase,
                                                    int* __restrict__ rptr,
                                                    int2* __restrict__ sedge) {
  const int b = blockIdx.x;
  const int t = threadIdx.x;
  __shared__ int cnt[512];
  __shared__ int excl[512];
  __shared__ int s[256];
  cnt[t] = 0;
  cnt[t + 256] = 0;
  __syncthreads();
  const int ebase = bbase[b];
  const int ecnt = bbase[b + 1] - ebase;
  for (int i = t; i < ecnt; i += 256)
    atomicAdd(&cnt[((unsigned)binned[ebase + i].x) >> 17], 1);
  __syncthreads();
  int c0 = cnt[2 * t], c1 = cnt[2 * t + 1];
  s[t] = c0 + c1;
  __syncthreads();
  for (int off = 1; off < 256; off <<= 1) {
    int y = (t >= off) ? s[t - off] : 0;
    __syncthreads();
    s[t] += y;
    __syncthreads();
  }
  int e = s[t] - (c0 + c1);
  excl[2 * t] = e;
  excl[2 * t + 1] = e + c0;
  __syncthreads();
  for (int i = t; i < 512; i += 256) {
    int node = b * 512 + i;
    if (node < N_NODES) rptr[node] = ebase + excl[i];
  }
  __syncthreads();
  for (int i = t; i < ecnt; i += 256) {
    int2 e2 = binned[ebase + i];
    int lrow = ((unsigned)e2.x) >> 17;
    int col = e2.x & 0x1FFFF;
    int p = atomicAdd(&excl[lrow], 1);
    sedge[ebase + p] = make_int2(col, e2.y);
  }
}

// ------------- GEMM1 (MFMA): support1 = bf16(X @ W1), row-major out ---------
// M=100000, N=256 (full width per block -> X read ONCE), K=512.
// 128x256 block tile, 4 waves each 64x128 (4x8 fragments), BK=32.
// v3: DOUBLE-BUFFERED LDS + one barrier per K-step (T3 minimum-2-phase).
// acc[4][8] = 128 AGPR + 136 VGPR = 1 wave/SIMD -> no inter-block latency
// hiding exists; the v2 single-buffer loop serialized {issue -> full HBM/L3
// latency -> compute} every K-step. Now stage(k+1) is issued right after the
// barrier and lands during compute(k); the next barrier's vmcnt(0) drain is
// short. Swizzle scheme (pre-swizzled global source, XOR on ds_read) kept.
__global__ __launch_bounds__(256) void k_gemm1(const float* __restrict__ X,
                                               const unsigned short* __restrict__ Wt,
                                               unsigned short* __restrict__ C) {
  __shared__ float AsF[2 * 128 * 32];           // 2 x 16 KB fp32, chunk-swizzled
  __shared__ unsigned short BsS[2 * 256 * 32];  // 2 x 16 KB bf16, chunk-swizzled
  const int t = threadIdx.x;
  const int wave = t >> 6, lane = t & 63;
  const int q = lane >> 4, r = lane & 15;
  const int wm = (wave >> 1) * 64;   // 0 or 64
  const int wn = (wave & 1) * 128;   // 0 or 128
  const int m0 = blockIdx.x * 128;

  // staging geometry (k0-invariant): each wave round writes 1 KB linear LDS.
  // A: row = j*32 + wave*8 + (lane>>3), chunk(16B)= lane&7, swz: gc = c ^ (row&7)
  // B: row = j*64 + wave*16 + (lane>>2), chunk    = lane&3, swz: gc = c ^ (row&3)
  const int ar_base = wave * 8 + (lane >> 3);
  const int ac = lane & 7;
  const int br_base = wave * 16 + (lane >> 2);
  const int bc = lane & 3;

  // precomputed per-lane global source pointers (advance by k0 each step)
  const float* agp[4];
  const unsigned short* bgp[4];
#pragma unroll
  for (int j = 0; j < 4; j++) {
    int row = ar_base + j * 32;
    int gr = m0 + row;
    if (gr > N_NODES - 1) gr = N_NODES - 1;
    agp[j] = &X[(size_t)gr * IN_FEAT + ((ac ^ (row & 7)) << 2)];
    int brow = br_base + j * 64;
    bgp[j] = &Wt[(size_t)brow * IN_FEAT + ((bc ^ (brow & 3)) << 3)];
  }

  f32x4 acc[4][8];
#pragma unroll
  for (int mi = 0; mi < 4; mi++)
#pragma unroll
    for (int ni = 0; ni < 8; ni++) acc[mi][ni] = (f32x4){0.f, 0.f, 0.f, 0.f};

  // prologue: stage k0=0 into buffer 0
#pragma unroll
  for (int j = 0; j < 4; j++)
    gl16(agp[j], (char*)AsF + j * 4096 + wave * 1024);
#pragma unroll
  for (int j = 0; j < 4; j++)
    gl16(bgp[j], (char*)BsS + j * 4096 + wave * 1024);

  int cur = 0;
  for (int k0 = 0; k0 < IN_FEAT; k0 += 32) {
    __syncthreads();   // buf[cur] staged (vmcnt drain) + prev compute done

    // issue next tile's loads into buf[cur^1] — lands under compute below
    if (k0 + 32 < IN_FEAT) {
      int nb = (cur ^ 1) * 16384;  // byte offset of the other buffer
#pragma unroll
      for (int j = 0; j < 4; j++)
        gl16(agp[j] + k0 + 32, (char*)AsF + nb + j * 4096 + wave * 1024);
#pragma unroll
      for (int j = 0; j < 4; j++)
        gl16(bgp[j] + k0 + 32, (char*)BsS + nb + j * 4096 + wave * 1024);
    }

    // compute from buf[cur]
    const float* Abuf = AsF + cur * 4096;            // floats
    const unsigned short* Bbuf = BsS + cur * 8192;   // ushorts
    short8x af[4];
#pragma unroll
    for (int mi = 0; mi < 4; mi++) {
      int row = wm + mi * 16 + r;
      int sw = row & 7;
      const float* Ar = &Abuf[row * 32];
      f32x4 a0 = *(const f32x4*)&Ar[(((q << 1)) ^ sw) << 2];
      f32x4 a1 = *(const f32x4*)&Ar[(((q << 1) | 1) ^ sw) << 2];
      short8x a;
      a[0] = (short)f2bf(a0[0]); a[1] = (short)f2bf(a0[1]);
      a[2] = (short)f2bf(a0[2]); a[3] = (short)f2bf(a0[3]);
      a[4] = (short)f2bf(a1[0]); a[5] = (short)f2bf(a1[1]);
      a[6] = (short)f2bf(a1[2]); a[7] = (short)f2bf(a1[3]);
      af[mi] = a;
    }
#pragma unroll
    for (int ni = 0; ni < 8; ni++) {
      int row = wn + ni * 16 + r;
      short8x b = *(const short8x*)&Bbuf[row * 32 + ((q ^ (row & 3)) << 3)];
#pragma unroll
      for (int mi = 0; mi < 4; mi++)
        acc[mi][ni] = __builtin_amdgcn_mfma_f32_16x16x32_bf16(af[mi], b,
                                                              acc[mi][ni], 0, 0, 0);
    }
    cur ^= 1;
  }
#pragma unroll
  for (int mi = 0; mi < 4; mi++) {
#pragma unroll
    for (int ni = 0; ni < 8; ni++) {
      int col = wn + ni * 16 + r;
#pragma unroll
      for (int reg = 0; reg < 4; reg++) {
        int row = m0 + wm + mi * 16 + q * 4 + reg;
        if (row < N_NODES)
          C[(size_t)row * HIDDEN + col] = f2bf(acc[mi][ni][reg]);
      }
    }
  }
}

// ---------------- SpMM1: h = bf16(relu(A @ support1 + b1)) ------------------
// one wave per node; 2 edge-slots x 32 lanes x ushort8 (16 B) per row.
// launched as TWO half-grids (diagnostic: expose other kernels in top-5)
__global__ __launch_bounds__(256) void k_spmm1(const unsigned short* __restrict__ S,
                                               const int* __restrict__ rptr,
                                               const int2* __restrict__ sedge,
                                               const float* __restrict__ b1,
                                               unsigned short* __restrict__ H,
                                               int node_off) {
  const int node = node_off + ((blockIdx.x * blockDim.x + threadIdx.x) >> 6);
  const int lane = threadIdx.x & 63;
  const int half = lane >> 5;   // edge slot 0/1
  const int fl = lane & 31;     // feature group: feats fl*8 .. fl*8+7
  int e0 = rptr[node], e1 = rptr[node + 1];
  float a[8];
#pragma unroll
  for (int k = 0; k < 8; k++) a[k] = 0.f;
  for (int base = e0; base < e1; base += 64) {
    int rem = min(64, e1 - base);
    int c = 0;
    float v = 0.f;
    if (lane < rem) {
      int2 e = sedge[base + lane];
      c = e.x;
      v = __int_as_float(e.y);
    }
    int iters = (rem + 1) >> 1;
#pragma unroll 8
    for (int j = 0; j < iters; j++) {
      int idx = 2 * j + half;            // inactive tail: c=0,v=0 -> adds 0
      int cj = __shfl(c, idx);
      float vj = __shfl(v, idx);
      short8x s8 = *(const short8x*)&S[(size_t)cj * HIDDEN + fl * 8];
#pragma unroll
      for (int k = 0; k < 8; k++)
        a[k] += vj * bf2f((unsigned short)s8[k]);
    }
  }
#pragma unroll
  for (int k = 0; k < 8; k++) a[k] += __shfl_xor(a[k], 32);
  if (half == 0) {
    float4 b0 = *(const float4*)&b1[fl * 8];
    float4 b4 = *(const float4*)&b1[fl * 8 + 4];
    u16x8 o;
    o[0] = f2bf(fmaxf(a[0] + b0.x, 0.f));
    o[1] = f2bf(fmaxf(a[1] + b0.y, 0.f));
    o[2] = f2bf(fmaxf(a[2] + b0.z, 0.f));
    o[3] = f2bf(fmaxf(a[3] + b0.w, 0.f));
    o[4] = f2bf(fmaxf(a[4] + b4.x, 0.f));
    o[5] = f2bf(fmaxf(a[5] + b4.y, 0.f));
    o[6] = f2bf(fmaxf(a[6] + b4.z, 0.f));
    o[7] = f2bf(fmaxf(a[7] + b4.w, 0.f));
    *(u16x8*)&H[(size_t)node * HIDDEN + fl * 8] = o;
  }
}

// ------- GEMM2 (MFMA): support2 = bf16(H @ W2t^T), 48-col, K=256 ------------
// grid = ceil(100000/64), block 256 = 4 waves; wave = 16 rows x 48 cols.
// A,B frags loaded straight from global (H bf16, W2t bf16 L2-resident).
__global__ __launch_bounds__(256) void k_gemm2(const unsigned short* __restrict__ H,
                                               const unsigned short* __restrict__ W2t,
                                               unsigned short* __restrict__ S2) {
  const int t = threadIdx.x;
  const int wave = t >> 6, lane = t & 63;
  const int q = lane >> 4, r = lane & 15;
  const int m0 = blockIdx.x * 64 + wave * 16;

  f32x4 acc[3];
#pragma unroll
  for (int n = 0; n < 3; n++) acc[n] = (f32x4){0.f, 0.f, 0.f, 0.f};

  int arow = m0 + r;
  if (arow > N_NODES - 1) arow = N_NODES - 1;
  const unsigned short* Arow = &H[(size_t)arow * HIDDEN + q * 8];

#pragma unroll
  for (int k0 = 0; k0 < HIDDEN; k0 += 32) {
    short8x af = *(const short8x*)&Arow[k0];
    short8x bf0 = *(const short8x*)&W2t[(0 * 16 + r) * HIDDEN + k0 + q * 8];
    short8x bf1 = *(const short8x*)&W2t[(1 * 16 + r) * HIDDEN + k0 + q * 8];
    short8x bf2 = *(const short8x*)&W2t[(2 * 16 + r) * HIDDEN + k0 + q * 8];
    acc[0] = __builtin_amdgcn_mfma_f32_16x16x32_bf16(af, bf0, acc[0], 0, 0, 0);
    acc[1] = __builtin_amdgcn_mfma_f32_16x16x32_bf16(af, bf1, acc[1], 0, 0, 0);
    acc[2] = __builtin_amdgcn_mfma_f32_16x16x32_bf16(af, bf2, acc[2], 0, 0, 0);
  }
  // C layout: col = r, row = q*4+reg
#pragma unroll
  for (int n = 0; n < 3; n++) {
#pragma unroll
    for (int reg = 0; reg < 4; reg++) {
      int row = m0 + q * 4 + reg;
      if (row < N_NODES)
        S2[(size_t)row * S2_STRIDE + n * 16 + r] = f2bf(acc[n][reg]);
    }
  }
}

// --- SpMM2 + bias + log_softmax: 8 edge-slots x 8 lanes x 6 bf16 (12 B) -----
__global__ __launch_bounds__(256) void k_spmm2(const unsigned short* __restrict__ S2,
                                               const int* __restrict__ rptr,
                                               const int2* __restrict__ sedge,
                                               const float* __restrict__ b2,
                                               float* __restrict__ out) {
  const int node = (blockIdx.x * blockDim.x + threadIdx.x) >> 6;
  const int lane = threadIdx.x & 63;
  const int q = lane >> 3;    // edge slot 0..7
  const int fl = lane & 7;    // feats fl*6 .. fl*6+5 (covers 0..47 incl pad)
  int e0 = rptr[node], e1 = rptr[node + 1];
  float a[6] = {0.f, 0.f, 0.f, 0.f, 0.f, 0.f};
  for (int base = e0; base < e1; base += 64) {
    int rem = min(64, e1 - base);
    int c = 0;
    float v = 0.f;
    if (lane < rem) {
      int2 e = sedge[base + lane];
      c = e.x;
      v = __int_as_float(e.y);
    }
    int iters = (rem + 7) >> 3;
#pragma unroll 8
    for (int j = 0; j < iters; j++) {
      int idx = 8 * j + q;               // inactive tail: c=0,v=0 -> adds 0
      int cj = __shfl(c, idx);
      float vj = __shfl(v, idx);
      u32x3 w = *(const u32x3*)&S2[(size_t)cj * S2_STRIDE + fl * 6];
      a[0] += vj * bflo(w.x);
      a[1] += vj * bfhi(w.x);
      a[2] += vj * bflo(w.y);
      a[3] += vj * bfhi(w.y);
      a[4] += vj * bflo(w.z);
      a[5] += vj * bfhi(w.z);
    }
  }
#pragma unroll
  for (int k = 0; k < 6; k++) {
    a[k] += __shfl_xor(a[k], 8);
    a[k] += __shfl_xor(a[k], 16);
    a[k] += __shfl_xor(a[k], 32);
  }
  float x[6];
  float mloc = -INFINITY;
#pragma unroll
  for (int k = 0; k < 6; k++) {
    int f = fl * 6 + k;
    x[k] = (f < N_CLASS) ? (a[k] + b2[f]) : -INFINITY;
    mloc = fmaxf(mloc, x[k]);
  }
#pragma unroll
  for (int o = 1; o < 8; o <<= 1) mloc = fmaxf(mloc, __shfl_xor(mloc, o));
  float sloc = 0.f;
#pragma unroll
  for (int k = 0; k < 6; k++)
    sloc += (fl * 6 + k < N_CLASS) ? expf(x[k] - mloc) : 0.f;
#pragma unroll
  for (int o = 1; o < 8; o <<= 1) sloc += __shfl_xor(sloc, o);
  float ls = logf(sloc);
  if (q == 0) {
#pragma unroll
    for (int k = 0; k < 6; k++) {
      int f = fl * 6 + k;
      if (f < N_CLASS) out[(size_t)node * N_CLASS + f] = (x[k] - mloc) - ls;
    }
  }
}

// ---------------------------------------------------------------------------
extern "C" void kernel_launch(void* const* d_in, const int* in_sizes, int n_in,
                              void* d_out, int out_size, void* d_ws, size_t ws_size,
                              hipStream_t stream) {
  const float* x    = (const float*)d_in[0];
  const float* w1   = (const float*)d_in[1];
  const float* b1   = (const float*)d_in[2];
  const float* w2   = (const float*)d_in[3];
  const float* b2   = (const float*)d_in[4];
  const float* eval = (const float*)d_in[5];
  const int*   erow = (const int*)d_in[6];
  const int*   ecol = (const int*)d_in[7];
  float* out = (float*)d_out;

  char* ws = (char*)d_ws;
  unsigned short* support1 = (unsigned short*)(ws + OFF_SUPPORT1);
  unsigned short* h        = (unsigned short*)(ws + OFF_H);
  unsigned short* support2 = (unsigned short*)(ws + OFF_SUPPORT2);
  unsigned short* w1t = (unsigned short*)(ws + OFF_W1T);
  unsigned short* w2t = (unsigned short*)(ws + OFF_W2T);
  int*   rptr   = (int*)(ws + OFF_RPTR);
  int*   bcnt   = (int*)(ws + OFF_BCNT);
  int*   bbase  = (int*)(ws + OFF_BBASE);
  int*   bcur   = (int*)(ws + OFF_BCUR);
  int2*  binned = (int2*)(ws + OFF_BINNED);
  int2*  sedge  = (int2*)(ws + OFF_SEDGE);

  // ---- CSR build (bucketed) + weight prep ----
  hipMemsetAsync(bcnt, 0, N_BUCKETS * 4, stream);
  k_bincnt<<<512, 256, 0, stream>>>(erow, bcnt, w1, w1t, w2, w2t);
  k_binscan<<<1, 256, 0, stream>>>(bcnt, bbase, bcur, rptr);
  k_binscatter<<<N_SC_BLOCKS, 256, 0, stream>>>(erow, ecol, eval, bcur, binned);
  k_bucket_csr<<<N_BUCKETS, 256, 0, stream>>>(binned, bbase, rptr, sedge);

  // ---- layer 1 ----
  k_gemm1<<<dim3((N_NODES + 127) / 128, 1), 256, 0, stream>>>(x, w1t, support1);
  k_spmm1<<<N_NODES / 8, 256, 0, stream>>>(support1, rptr, sedge, b1, h, 0);
  k_spmm1<<<N_NODES / 8, 256, 0, stream>>>(support1, rptr, sedge, b1, h, N_NODES / 2);

  // ---- layer 2 ----
  k_gemm2<<<(N_NODES + 63) / 64, 256, 0, stream>>>(h, w2t, support2);
  k_spmm2<<<N_NODES / 4, 256, 0, stream>>>(support2, rptr, sedge, b2, out);
}

// Round 3
// 779.039 us; speedup vs baseline: 1.0349x; 1.0240x over previous
//
#include <hip/hip_runtime.h>
#include <cstdint>
#include <cstddef>

#define N_NODES 100000
#define N_EDGES 3200000
#define IN_FEAT 512
#define HIDDEN  256
#define N_CLASS 40
#define S2_STRIDE 48         // support2 rows padded 40 -> 48 bf16 (96 B)

#define N_BUCKETS 196        // ceil(100000 / 512), bucket = row >> 9
#define SC_CHUNK 4096        // edges per binscatter block (256 thr x 16)
#define N_SC_BLOCKS 782      // ceil(3.2e6 / 4096)

// ---------------------------------------------------------------------------
// Workspace layout (bytes), 256B-aligned
// ---------------------------------------------------------------------------
#define OFF_SUPPORT1 ((size_t)0)
#define OFF_H        ((size_t)51200000)
#define OFF_SUPPORT2 ((size_t)102400000)
#define OFF_W1T      ((size_t)112000000)
#define OFF_W2T      ((size_t)112262144)
#define OFF_RPTR     ((size_t)112286976)
#define OFF_BCNT     ((size_t)112687104)
#define OFF_BBASE    ((size_t)112688128)
#define OFF_BCUR     ((size_t)112689152)
#define OFF_BINNED   ((size_t)112690176)
#define OFF_SEDGE    ((size_t)138290176)

typedef __attribute__((ext_vector_type(8))) short short8x;
typedef __attribute__((ext_vector_type(4))) float f32x4;
typedef __attribute__((ext_vector_type(8))) unsigned short u16x8;
typedef __attribute__((ext_vector_type(3))) unsigned int u32x3;
typedef __attribute__((ext_vector_type(4))) unsigned int u32x4;

static __device__ __forceinline__ unsigned short f2bf(float f) {
  unsigned u = __float_as_uint(f);
  unsigned r = (u + 0x7FFFu + ((u >> 16) & 1u)) >> 16;  // RNE
  return (unsigned short)r;
}
static __device__ __forceinline__ float bf2f(unsigned short s) {
  return __uint_as_float(((unsigned)s) << 16);
}
static __device__ __forceinline__ float bflo(unsigned u) {
  return __uint_as_float(u << 16);
}
static __device__ __forceinline__ float bfhi(unsigned u) {
  return __uint_as_float(u & 0xFFFF0000u);
}

// async global->LDS, 16B per lane, dest = wave-uniform base + lane*16
static __device__ __forceinline__ void gl16(const void* g, void* l) {
  __builtin_amdgcn_global_load_lds(
      (const __attribute__((address_space(1))) unsigned int*)g,
      (__attribute__((address_space(3))) unsigned int*)l, 16, 0, 0);
}

// ------- bucket histogram + W1/W2 transpose/cast (merged, spare threads) ----
// grid 512 x 256 = 131072 threads: covers w1t (131072 elems) and w2t (12288)
__global__ __launch_bounds__(256) void k_bincnt(const int* __restrict__ erow,
                                                int* __restrict__ bcnt,
                                                const float* __restrict__ W1,
                                                unsigned short* __restrict__ W1t,
                                                const float* __restrict__ W2,
                                                unsigned short* __restrict__ W2t) {
  int tid = blockIdx.x * 256 + threadIdx.x;
  {
    int n = tid & 255;
    int k = tid >> 8;
    W1t[(size_t)n * IN_FEAT + k] = f2bf(W1[(size_t)k * HIDDEN + n]);
  }
  if (tid < 48 * HIDDEN) {
    int n = tid >> 8;          // 0..47
    int k = tid & 255;         // 0..255
    W2t[n * HIDDEN + k] = (n < N_CLASS) ? f2bf(W2[(size_t)k * N_CLASS + n]) : 0;
  }
  __shared__ int lh[256];
  lh[threadIdx.x] = 0;
  __syncthreads();
  int i = tid;
  int stride = gridDim.x * blockDim.x;
  for (; i < N_EDGES; i += stride) atomicAdd(&lh[erow[i] >> 9], 1);
  __syncthreads();
  if (threadIdx.x < N_BUCKETS) atomicAdd(&bcnt[threadIdx.x], lh[threadIdx.x]);
}

__global__ __launch_bounds__(256) void k_binscan(const int* __restrict__ bcnt,
                                                 int* __restrict__ bbase,
                                                 int* __restrict__ bcur,
                                                 int* __restrict__ rptr) {
  __shared__ int s[256];
  int t = threadIdx.x;
  int v = (t < N_BUCKETS) ? bcnt[t] : 0;
  s[t] = v;
  __syncthreads();
  for (int off = 1; off < 256; off <<= 1) {
    int y = (t >= off) ? s[t - off] : 0;
    __syncthreads();
    s[t] += y;
    __syncthreads();
  }
  if (t < N_BUCKETS) {
    int e = s[t] - v;
    bbase[t] = e;
    bcur[t] = e;
  }
  if (t == 0) {
    bbase[N_BUCKETS] = N_EDGES;
    rptr[N_NODES] = N_EDGES;
  }
}

__global__ __launch_bounds__(256) void k_binscatter(const int* __restrict__ erow,
                                                    const int* __restrict__ ecol,
                                                    const float* __restrict__ eval,
                                                    int* __restrict__ bcur,
                                                    int2* __restrict__ binned) {
  __shared__ int lcnt[256];
  __shared__ int lcur[256];
  const int t = threadIdx.x;
  const int base = blockIdx.x * SC_CHUNK;
  lcnt[t] = 0;
  __syncthreads();
  int rows[16], cols[16], vals[16];
#pragma unroll
  for (int e = 0; e < 16; e++) {
    int i = base + t + e * 256;
    if (i < N_EDGES) {
      rows[e] = erow[i];
      cols[e] = ecol[i];
      vals[e] = __float_as_int(eval[i]);
      atomicAdd(&lcnt[rows[e] >> 9], 1);
    } else {
      rows[e] = -1;
    }
  }
  __syncthreads();
  if (t < N_BUCKETS) lcur[t] = atomicAdd(&bcur[t], lcnt[t]);
  __syncthreads();
#pragma unroll
  for (int e = 0; e < 16; e++) {
    if (rows[e] >= 0) {
      int bkt = rows[e] >> 9;
      int p = atomicAdd(&lcur[bkt], 1);
      binned[p] = make_int2(((rows[e] & 511) << 17) | cols[e], vals[e]);
    }
  }
}

__global__ __launch_bounds__(256) void k_bucket_csr(const int2* __restrict__ binned,
                                                    const int* __restrict__ bbase,
                                                    int* __restrict__ rptr,
                                                    int2* __restrict__ sedge) {
  const int b = blockIdx.x;
  const int t = threadIdx.x;
  __shared__ int cnt[512];
  __shared__ int excl[512];
  __shared__ int s[256];
  cnt[t] = 0;
  cnt[t + 256] = 0;
  __syncthreads();
  const int ebase = bbase[b];
  const int ecnt = bbase[b + 1] - ebase;
  for (int i = t; i < ecnt; i += 256)
    atomicAdd(&cnt[((unsigned)binned[ebase + i].x) >> 17], 1);
  __syncthreads();
  int c0 = cnt[2 * t], c1 = cnt[2 * t + 1];
  s[t] = c0 + c1;
  __syncthreads();
  for (int off = 1; off < 256; off <<= 1) {
    int y = (t >= off) ? s[t - off] : 0;
    __syncthreads();
    s[t] += y;
    __syncthreads();
  }
  int e = s[t] - (c0 + c1);
  excl[2 * t] = e;
  excl[2 * t + 1] = e + c0;
  __syncthreads();
  for (int i = t; i < 512; i += 256) {
    int node = b * 512 + i;
    if (node < N_NODES) rptr[node] = ebase + excl[i];
  }
  __syncthreads();
  for (int i = t; i < ecnt; i += 256) {
    int2 e2 = binned[ebase + i];
    int lrow = ((unsigned)e2.x) >> 17;
    int col = e2.x & 0x1FFFF;
    int p = atomicAdd(&excl[lrow], 1);
    sedge[ebase + p] = make_int2(col, e2.y);
  }
}

// ------------- GEMM1 (MFMA): support1 = bf16(X @ W1), row-major out ---------
// M=100000, N=256 (full width per block -> X read ONCE), K=512.
// v4: 64x256 block tile, 4 waves each 64x64 -> acc[4][4] = 64 acc regs.
// v3's acc[4][8]=128 acc + 136 VGPR = 264 total regs -> 1 wave/SIMD -> one
// block/CU -> every vmcnt/lgkm/MFMA stall fully exposed (all pipes <15%).
// Now total regs < 256 (__launch_bounds__(256,2)) -> 2 waves/SIMD = TWO
// INDEPENDENT blocks/CU (separate barriers: one block computes while the
// other drains). LDS dbuf 48 KB/block (2x fits in 160 KB). Grid 1563,
// X still read exactly once. gl16 staging + source-swizzle kept.
__global__ __launch_bounds__(256, 2) void k_gemm1(const float* __restrict__ X,
                                                  const unsigned short* __restrict__ Wt,
                                                  unsigned short* __restrict__ C) {
  __shared__ float AsF[2 * 64 * 32];            // 2 x 8 KB fp32, chunk-swizzled
  __shared__ unsigned short BsS[2 * 256 * 32];  // 2 x 16 KB bf16, chunk-swizzled
  const int t = threadIdx.x;
  const int wave = t >> 6, lane = t & 63;
  const int q = lane >> 4, r = lane & 15;
  const int wn = wave * 64;          // wave's N-offset (0/64/128/192)
  const int m0 = blockIdx.x * 64;

  // staging geometry (k0-invariant): 1 KB linear LDS per gl16 round.
  // A (64x32 f32, 128B/row): 2 rounds/wave; row = wave*16 + j*8 + (lane>>3),
  //   chunk(16B) = lane&7, source swz: gc = chunk ^ (row&7)
  // B (256x32 bf16, 64B/row): 4 rounds/wave; row = wave*64 + j*16 + (lane>>2),
  //   chunk = lane&3, source swz: gc = chunk ^ (row&3)
  const int ar_base = wave * 16 + (lane >> 3);
  const int ac = lane & 7;
  const int br_base = wave * 64 + (lane >> 2);
  const int bc = lane & 3;

  const float* agp[2];
  const unsigned short* bgp[4];
#pragma unroll
  for (int j = 0; j < 2; j++) {
    int row = ar_base + j * 8;
    int gr = m0 + row;
    if (gr > N_NODES - 1) gr = N_NODES - 1;
    agp[j] = &X[(size_t)gr * IN_FEAT + ((ac ^ (row & 7)) << 2)];
  }
#pragma unroll
  for (int j = 0; j < 4; j++) {
    int brow = br_base + j * 16;
    bgp[j] = &Wt[(size_t)brow * IN_FEAT + ((bc ^ (brow & 3)) << 3)];
  }

  f32x4 acc[4][4];
#pragma unroll
  for (int mi = 0; mi < 4; mi++)
#pragma unroll
    for (int ni = 0; ni < 4; ni++) acc[mi][ni] = (f32x4){0.f, 0.f, 0.f, 0.f};

  // prologue: stage k0=0 into buffer 0
#pragma unroll
  for (int j = 0; j < 2; j++)
    gl16(agp[j], (char*)AsF + wave * 2048 + j * 1024);
#pragma unroll
  for (int j = 0; j < 4; j++)
    gl16(bgp[j], (char*)BsS + wave * 4096 + j * 1024);

  int cur = 0;
  for (int k0 = 0; k0 < IN_FEAT; k0 += 32) {
    __syncthreads();   // buf[cur] staged (vmcnt drain) + prev compute done

    // issue next tile's loads into buf[cur^1] — lands under compute below
    if (k0 + 32 < IN_FEAT) {
      int nbA = (cur ^ 1) * 8192;   // byte offset of other A buffer
      int nbB = (cur ^ 1) * 16384;  // byte offset of other B buffer
#pragma unroll
      for (int j = 0; j < 2; j++)
        gl16(agp[j] + k0 + 32, (char*)AsF + nbA + wave * 2048 + j * 1024);
#pragma unroll
      for (int j = 0; j < 4; j++)
        gl16(bgp[j] + k0 + 32, (char*)BsS + nbB + wave * 4096 + j * 1024);
    }

    // compute from buf[cur]
    const float* Abuf = AsF + cur * 2048;            // floats
    const unsigned short* Bbuf = BsS + cur * 8192;   // ushorts
    short8x af[4];
#pragma unroll
    for (int mi = 0; mi < 4; mi++) {
      int row = mi * 16 + r;
      int sw = row & 7;
      const float* Ar = &Abuf[row * 32];
      f32x4 a0 = *(const f32x4*)&Ar[(((q << 1)) ^ sw) << 2];
      f32x4 a1 = *(const f32x4*)&Ar[(((q << 1) | 1) ^ sw) << 2];
      short8x a;
      a[0] = (short)f2bf(a0[0]); a[1] = (short)f2bf(a0[1]);
      a[2] = (short)f2bf(a0[2]); a[3] = (short)f2bf(a0[3]);
      a[4] = (short)f2bf(a1[0]); a[5] = (short)f2bf(a1[1]);
      a[6] = (short)f2bf(a1[2]); a[7] = (short)f2bf(a1[3]);
      af[mi] = a;
    }
#pragma unroll
    for (int ni = 0; ni < 4; ni++) {
      int row = wn + ni * 16 + r;
      short8x b = *(const short8x*)&Bbuf[row * 32 + ((q ^ (row & 3)) << 3)];
#pragma unroll
      for (int mi = 0; mi < 4; mi++)
        acc[mi][ni] = __builtin_amdgcn_mfma_f32_16x16x32_bf16(af[mi], b,
                                                              acc[mi][ni], 0, 0, 0);
    }
    cur ^= 1;
  }
#pragma unroll
  for (int mi = 0; mi < 4; mi++) {
#pragma unroll
    for (int ni = 0; ni < 4; ni++) {
      int col = wn + ni * 16 + r;
#pragma unroll
      for (int reg = 0; reg < 4; reg++) {
        int row = m0 + mi * 16 + q * 4 + reg;
        if (row < N_NODES)
          C[(size_t)row * HIDDEN + col] = f2bf(acc[mi][ni][reg]);
      }
    }
  }
}

// ---------------- SpMM1: h = bf16(relu(A @ support1 + b1)) ------------------
// one wave per node; 2 edge-slots x 32 lanes x ushort8 (16 B) per row.
// launched as TWO half-grids (diagnostic: expose other kernels in top-5)
__global__ __launch_bounds__(256) void k_spmm1(const unsigned short* __restrict__ S,
                                               const int* __restrict__ rptr,
                                               const int2* __restrict__ sedge,
                                               const float* __restrict__ b1,
                                               unsigned short* __restrict__ H,
                                               int node_off) {
  const int node = node_off + ((blockIdx.x * blockDim.x + threadIdx.x) >> 6);
  const int lane = threadIdx.x & 63;
  const int half = lane >> 5;   // edge slot 0/1
  const int fl = lane & 31;     // feature group: feats fl*8 .. fl*8+7
  int e0 = rptr[node], e1 = rptr[node + 1];
  float a[8];
#pragma unroll
  for (int k = 0; k < 8; k++) a[k] = 0.f;
  for (int base = e0; base < e1; base += 64) {
    int rem = min(64, e1 - base);
    int c = 0;
    float v = 0.f;
    if (lane < rem) {
      int2 e = sedge[base + lane];
      c = e.x;
      v = __int_as_float(e.y);
    }
    int iters = (rem + 1) >> 1;
#pragma unroll 8
    for (int j = 0; j < iters; j++) {
      int idx = 2 * j + half;            // inactive tail: c=0,v=0 -> adds 0
      int cj = __shfl(c, idx);
      float vj = __shfl(v, idx);
      short8x s8 = *(const short8x*)&S[(size_t)cj * HIDDEN + fl * 8];
#pragma unroll
      for (int k = 0; k < 8; k++)
        a[k] += vj * bf2f((unsigned short)s8[k]);
    }
  }
#pragma unroll
  for (int k = 0; k < 8; k++) a[k] += __shfl_xor(a[k], 32);
  if (half == 0) {
    float4 b0 = *(const float4*)&b1[fl * 8];
    float4 b4 = *(const float4*)&b1[fl * 8 + 4];
    u16x8 o;
    o[0] = f2bf(fmaxf(a[0] + b0.x, 0.f));
    o[1] = f2bf(fmaxf(a[1] + b0.y, 0.f));
    o[2] = f2bf(fmaxf(a[2] + b0.z, 0.f));
    o[3] = f2bf(fmaxf(a[3] + b0.w, 0.f));
    o[4] = f2bf(fmaxf(a[4] + b4.x, 0.f));
    o[5] = f2bf(fmaxf(a[5] + b4.y, 0.f));
    o[6] = f2bf(fmaxf(a[6] + b4.z, 0.f));
    o[7] = f2bf(fmaxf(a[7] + b4.w, 0.f));
    *(u16x8*)&H[(size_t)node * HIDDEN + fl * 8] = o;
  }
}

// ------- GEMM2 (MFMA): support2 = bf16(H @ W2t^T), 48-col, K=256 ------------
// grid = ceil(100000/64), block 256 = 4 waves; wave = 16 rows x 48 cols.
// A,B frags loaded straight from global (H bf16, W2t bf16 L2-resident).
__global__ __launch_bounds__(256) void k_gemm2(const unsigned short* __restrict__ H,
                                               const unsigned short* __restrict__ W2t,
                                               unsigned short* __restrict__ S2) {
  const int t = threadIdx.x;
  const int wave = t >> 6, lane = t & 63;
  const int q = lane >> 4, r = lane & 15;
  const int m0 = blockIdx.x * 64 + wave * 16;

  f32x4 acc[3];
#pragma unroll
  for (int n = 0; n < 3; n++) acc[n] = (f32x4){0.f, 0.f, 0.f, 0.f};

  int arow = m0 + r;
  if (arow > N_NODES - 1) arow = N_NODES - 1;
  const unsigned short* Arow = &H[(size_t)arow * HIDDEN + q * 8];

#pragma unroll
  for (int k0 = 0; k0 < HIDDEN; k0 += 32) {
    short8x af = *(const short8x*)&Arow[k0];
    short8x bf0 = *(const short8x*)&W2t[(0 * 16 + r) * HIDDEN + k0 + q * 8];
    short8x bf1 = *(const short8x*)&W2t[(1 * 16 + r) * HIDDEN + k0 + q * 8];
    short8x bf2 = *(const short8x*)&W2t[(2 * 16 + r) * HIDDEN + k0 + q * 8];
    acc[0] = __builtin_amdgcn_mfma_f32_16x16x32_bf16(af, bf0, acc[0], 0, 0, 0);
    acc[1] = __builtin_amdgcn_mfma_f32_16x16x32_bf16(af, bf1, acc[1], 0, 0, 0);
    acc[2] = __builtin_amdgcn_mfma_f32_16x16x32_bf16(af, bf2, acc[2], 0, 0, 0);
  }
  // C layout: col = r, row = q*4+reg
#pragma unroll
  for (int n = 0; n < 3; n++) {
#pragma unroll
    for (int reg = 0; reg < 4; reg++) {
      int row = m0 + q * 4 + reg;
      if (row < N_NODES)
        S2[(size_t)row * S2_STRIDE + n * 16 + r] = f2bf(acc[n][reg]);
    }
  }
}

// --- SpMM2 + bias + log_softmax: 8 edge-slots x 8 lanes x 6 bf16 (12 B) -----
__global__ __launch_bounds__(256) void k_spmm2(const unsigned short* __restrict__ S2,
                                               const int* __restrict__ rptr,
                                               const int2* __restrict__ sedge,
                                               const float* __restrict__ b2,
                                               float* __restrict__ out) {
  const int node = (blockIdx.x * blockDim.x + threadIdx.x) >> 6;
  const int lane = threadIdx.x & 63;
  const int q = lane >> 3;    // edge slot 0..7
  const int fl = lane & 7;    // feats fl*6 .. fl*6+5 (covers 0..47 incl pad)
  int e0 = rptr[node], e1 = rptr[node + 1];
  float a[6] = {0.f, 0.f, 0.f, 0.f, 0.f, 0.f};
  for (int base = e0; base < e1; base += 64) {
    int rem = min(64, e1 - base);
    int c = 0;
    float v = 0.f;
    if (lane < rem) {
      int2 e = sedge[base + lane];
      c = e.x;
      v = __int_as_float(e.y);
    }
    int iters = (rem + 7) >> 3;
#pragma unroll 8
    for (int j = 0; j < iters; j++) {
      int idx = 8 * j + q;               // inactive tail: c=0,v=0 -> adds 0
      int cj = __shfl(c, idx);
      float vj = __shfl(v, idx);
      u32x3 w = *(const u32x3*)&S2[(size_t)cj * S2_STRIDE + fl * 6];
      a[0] += vj * bflo(w.x);
      a[1] += vj * bfhi(w.x);
      a[2] += vj * bflo(w.y);
      a[3] += vj * bfhi(w.y);
      a[4] += vj * bflo(w.z);
      a[5] += vj * bfhi(w.z);
    }
  }
#pragma unroll
  for (int k = 0; k < 6; k++) {
    a[k] += __shfl_xor(a[k], 8);
    a[k] += __shfl_xor(a[k], 16);
    a[k] += __shfl_xor(a[k], 32);
  }
  float x[6];
  float mloc = -INFINITY;
#pragma unroll
  for (int k = 0; k < 6; k++) {
    int f = fl * 6 + k;
    x[k] = (f < N_CLASS) ? (a[k] + b2[f]) : -INFINITY;
    mloc = fmaxf(mloc, x[k]);
  }
#pragma unroll
  for (int o = 1; o < 8; o <<= 1) mloc = fmaxf(mloc, __shfl_xor(mloc, o));
  float sloc = 0.f;
#pragma unroll
  for (int k = 0; k < 6; k++)
    sloc += (fl * 6 + k < N_CLASS) ? expf(x[k] - mloc) : 0.f;
#pragma unroll
  for (int o = 1; o < 8; o <<= 1) sloc += __shfl_xor(sloc, o);
  float ls = logf(sloc);
  if (q == 0) {
#pragma unroll
    for (int k = 0; k < 6; k++) {
      int f = fl * 6 + k;
      if (f < N_CLASS) out[(size_t)node * N_CLASS + f] = (x[k] - mloc) - ls;
    }
  }
}

// ---------------------------------------------------------------------------
extern "C" void kernel_launch(void* const* d_in, const int* in_sizes, int n_in,
                              void* d_out, int out_size, void* d_ws, size_t ws_size,
                              hipStream_t stream) {
  const float* x    = (const float*)d_in[0];
  const float* w1   = (const float*)d_in[1];
  const float* b1   = (const float*)d_in[2];
  const float* w2   = (const float*)d_in[3];
  const float* b2   = (const float*)d_in[4];
  const float* eval = (const float*)d_in[5];
  const int*   erow = (const int*)d_in[6];
  const int*   ecol = (const int*)d_in[7];
  float* out = (float*)d_out;

  char* ws = (char*)d_ws;
  unsigned short* support1 = (unsigned short*)(ws + OFF_SUPPORT1);
  unsigned short* h        = (unsigned short*)(ws + OFF_H);
  unsigned short* support2 = (unsigned short*)(ws + OFF_SUPPORT2);
  unsigned short* w1t = (unsigned short*)(ws + OFF_W1T);
  unsigned short* w2t = (unsigned short*)(ws + OFF_W2T);
  int*   rptr   = (int*)(ws + OFF_RPTR);
  int*   bcnt   = (int*)(ws + OFF_BCNT);
  int*   bbase  = (int*)(ws + OFF_BBASE);
  int*   bcur   = (int*)(ws + OFF_BCUR);
  int2*  binned = (int2*)(ws + OFF_BINNED);
  int2*  sedge  = (int2*)(ws + OFF_SEDGE);

  // ---- CSR build (bucketed) + weight prep ----
  hipMemsetAsync(bcnt, 0, N_BUCKETS * 4, stream);
  k_bincnt<<<512, 256, 0, stream>>>(erow, bcnt, w1, w1t, w2, w2t);
  k_binscan<<<1, 256, 0, stream>>>(bcnt, bbase, bcur, rptr);
  k_binscatter<<<N_SC_BLOCKS, 256, 0, stream>>>(erow, ecol, eval, bcur, binned);
  k_bucket_csr<<<N_BUCKETS, 256, 0, stream>>>(binned, bbase, rptr, sedge);

  // ---- layer 1 ----
  k_gemm1<<<dim3((N_NODES + 63) / 64, 1), 256, 0, stream>>>(x, w1t, support1);
  k_spmm1<<<N_NODES / 8, 256, 0, stream>>>(support1, rptr, sedge, b1, h, 0);
  k_spmm1<<<N_NODES / 8, 256, 0, stream>>>(support1, rptr, sedge, b1, h, N_NODES / 2);

  // ---- layer 2 ----
  k_gemm2<<<(N_NODES + 63) / 64, 256, 0, stream>>>(h, w2t, support2);
  k_spmm2<<<N_NODES / 4, 256, 0, stream>>>(support2, rptr, sedge, b2, out);
}

// Round 4
// 777.777 us; speedup vs baseline: 1.0365x; 1.0016x over previous
//
#include <hip/hip_runtime.h>
#include <cstdint>
#include <cstddef>

#define N_NODES 100000
#define N_EDGES 3200000
#define IN_FEAT 512
#define HIDDEN  256
#define N_CLASS 40
#define S2_STRIDE 48         // support2 rows padded 40 -> 48 bf16 (96 B)

#define N_BUCKETS 196        // ceil(100000 / 512), bucket = row >> 9
#define SC_CHUNK 4096        // edges per binscatter block (256 thr x 16)
#define N_SC_BLOCKS 782      // ceil(3.2e6 / 4096)

// ---------------------------------------------------------------------------
// Workspace layout (bytes), 256B-aligned
// ---------------------------------------------------------------------------
#define OFF_SUPPORT1 ((size_t)0)
#define OFF_H        ((size_t)51200000)
#define OFF_SUPPORT2 ((size_t)102400000)
#define OFF_W1T      ((size_t)112000000)
#define OFF_W2T      ((size_t)112262144)
#define OFF_RPTR     ((size_t)112286976)
#define OFF_BCNT     ((size_t)112687104)
#define OFF_BBASE    ((size_t)112688128)
#define OFF_BCUR     ((size_t)112689152)
#define OFF_BINNED   ((size_t)112690176)
#define OFF_SEDGE    ((size_t)138290176)

typedef __attribute__((ext_vector_type(8))) short short8x;
typedef __attribute__((ext_vector_type(4))) float f32x4;
typedef __attribute__((ext_vector_type(8))) unsigned short u16x8;
typedef __attribute__((ext_vector_type(3))) unsigned int u32x3;
typedef __attribute__((ext_vector_type(4))) unsigned int u32x4;

static __device__ __forceinline__ unsigned short f2bf(float f) {
  unsigned u = __float_as_uint(f);
  unsigned r = (u + 0x7FFFu + ((u >> 16) & 1u)) >> 16;  // RNE
  return (unsigned short)r;
}
static __device__ __forceinline__ float bf2f(unsigned short s) {
  return __uint_as_float(((unsigned)s) << 16);
}
static __device__ __forceinline__ float bflo(unsigned u) {
  return __uint_as_float(u << 16);
}
static __device__ __forceinline__ float bfhi(unsigned u) {
  return __uint_as_float(u & 0xFFFF0000u);
}

// async global->LDS, 16B per lane, dest = wave-uniform base + lane*16
static __device__ __forceinline__ void gl16(const void* g, void* l) {
  __builtin_amdgcn_global_load_lds(
      (const __attribute__((address_space(1))) unsigned int*)g,
      (__attribute__((address_space(3))) unsigned int*)l, 16, 0, 0);
}

// ------- bucket histogram + W1/W2 transpose/cast (merged, spare threads) ----
// grid 512 x 256 = 131072 threads: covers w1t (131072 elems) and w2t (12288)
__global__ __launch_bounds__(256) void k_bincnt(const int* __restrict__ erow,
                                                int* __restrict__ bcnt,
                                                const float* __restrict__ W1,
                                                unsigned short* __restrict__ W1t,
                                                const float* __restrict__ W2,
                                                unsigned short* __restrict__ W2t) {
  int tid = blockIdx.x * 256 + threadIdx.x;
  {
    int n = tid & 255;
    int k = tid >> 8;
    W1t[(size_t)n * IN_FEAT + k] = f2bf(W1[(size_t)k * HIDDEN + n]);
  }
  if (tid < 48 * HIDDEN) {
    int n = tid >> 8;          // 0..47
    int k = tid & 255;         // 0..255
    W2t[n * HIDDEN + k] = (n < N_CLASS) ? f2bf(W2[(size_t)k * N_CLASS + n]) : 0;
  }
  __shared__ int lh[256];
  lh[threadIdx.x] = 0;
  __syncthreads();
  int i = tid;
  int stride = gridDim.x * blockDim.x;
  for (; i < N_EDGES; i += stride) atomicAdd(&lh[erow[i] >> 9], 1);
  __syncthreads();
  if (threadIdx.x < N_BUCKETS) atomicAdd(&bcnt[threadIdx.x], lh[threadIdx.x]);
}

__global__ __launch_bounds__(256) void k_binscan(const int* __restrict__ bcnt,
                                                 int* __restrict__ bbase,
                                                 int* __restrict__ bcur,
                                                 int* __restrict__ rptr) {
  __shared__ int s[256];
  int t = threadIdx.x;
  int v = (t < N_BUCKETS) ? bcnt[t] : 0;
  s[t] = v;
  __syncthreads();
  for (int off = 1; off < 256; off <<= 1) {
    int y = (t >= off) ? s[t - off] : 0;
    __syncthreads();
    s[t] += y;
    __syncthreads();
  }
  if (t < N_BUCKETS) {
    int e = s[t] - v;
    bbase[t] = e;
    bcur[t] = e;
  }
  if (t == 0) {
    bbase[N_BUCKETS] = N_EDGES;
    rptr[N_NODES] = N_EDGES;
  }
}

__global__ __launch_bounds__(256) void k_binscatter(const int* __restrict__ erow,
                                                    const int* __restrict__ ecol,
                                                    const float* __restrict__ eval,
                                                    int* __restrict__ bcur,
                                                    int2* __restrict__ binned) {
  __shared__ int lcnt[256];
  __shared__ int lcur[256];
  const int t = threadIdx.x;
  const int base = blockIdx.x * SC_CHUNK;
  lcnt[t] = 0;
  __syncthreads();
  int rows[16], cols[16], vals[16];
#pragma unroll
  for (int e = 0; e < 16; e++) {
    int i = base + t + e * 256;
    if (i < N_EDGES) {
      rows[e] = erow[i];
      cols[e] = ecol[i];
      vals[e] = __float_as_int(eval[i]);
      atomicAdd(&lcnt[rows[e] >> 9], 1);
    } else {
      rows[e] = -1;
    }
  }
  __syncthreads();
  if (t < N_BUCKETS) lcur[t] = atomicAdd(&bcur[t], lcnt[t]);
  __syncthreads();
#pragma unroll
  for (int e = 0; e < 16; e++) {
    if (rows[e] >= 0) {
      int bkt = rows[e] >> 9;
      int p = atomicAdd(&lcur[bkt], 1);
      binned[p] = make_int2(((rows[e] & 511) << 17) | cols[e], vals[e]);
    }
  }
}

__global__ __launch_bounds__(256) void k_bucket_csr(const int2* __restrict__ binned,
                                                    const int* __restrict__ bbase,
                                                    int* __restrict__ rptr,
                                                    int2* __restrict__ sedge) {
  const int b = blockIdx.x;
  const int t = threadIdx.x;
  __shared__ int cnt[512];
  __shared__ int excl[512];
  __shared__ int s[256];
  cnt[t] = 0;
  cnt[t + 256] = 0;
  __syncthreads();
  const int ebase = bbase[b];
  const int ecnt = bbase[b + 1] - ebase;
  for (int i = t; i < ecnt; i += 256)
    atomicAdd(&cnt[((unsigned)binned[ebase + i].x) >> 17], 1);
  __syncthreads();
  int c0 = cnt[2 * t], c1 = cnt[2 * t + 1];
  s[t] = c0 + c1;
  __syncthreads();
  for (int off = 1; off < 256; off <<= 1) {
    int y = (t >= off) ? s[t - off] : 0;
    __syncthreads();
    s[t] += y;
    __syncthreads();
  }
  int e = s[t] - (c0 + c1);
  excl[2 * t] = e;
  excl[2 * t + 1] = e + c0;
  __syncthreads();
  for (int i = t; i < 512; i += 256) {
    int node = b * 512 + i;
    if (node < N_NODES) rptr[node] = ebase + excl[i];
  }
  __syncthreads();
  for (int i = t; i < ecnt; i += 256) {
    int2 e2 = binned[ebase + i];
    int lrow = ((unsigned)e2.x) >> 17;
    int col = e2.x & 0x1FFFF;
    int p = atomicAdd(&excl[lrow], 1);
    sedge[ebase + p] = make_int2(col, e2.y);
  }
}

// ------------- GEMM1 (MFMA): support1 = bf16(X @ W1), row-major out ---------
// M=100000, N=256 (full width per block -> X read ONCE), K=512.
// v4 (kept): 64x256 block tile, acc[4][4]=64 acc regs -> 2 waves/SIMD;
// LDS dbuf, gl16 staging, source-swizzle. ~110 us (dropped out of top-5).
__global__ __launch_bounds__(256, 2) void k_gemm1(const float* __restrict__ X,
                                                  const unsigned short* __restrict__ Wt,
                                                  unsigned short* __restrict__ C) {
  __shared__ float AsF[2 * 64 * 32];            // 2 x 8 KB fp32, chunk-swizzled
  __shared__ unsigned short BsS[2 * 256 * 32];  // 2 x 16 KB bf16, chunk-swizzled
  const int t = threadIdx.x;
  const int wave = t >> 6, lane = t & 63;
  const int q = lane >> 4, r = lane & 15;
  const int wn = wave * 64;          // wave's N-offset (0/64/128/192)
  const int m0 = blockIdx.x * 64;

  const int ar_base = wave * 16 + (lane >> 3);
  const int ac = lane & 7;
  const int br_base = wave * 64 + (lane >> 2);
  const int bc = lane & 3;

  const float* agp[2];
  const unsigned short* bgp[4];
#pragma unroll
  for (int j = 0; j < 2; j++) {
    int row = ar_base + j * 8;
    int gr = m0 + row;
    if (gr > N_NODES - 1) gr = N_NODES - 1;
    agp[j] = &X[(size_t)gr * IN_FEAT + ((ac ^ (row & 7)) << 2)];
  }
#pragma unroll
  for (int j = 0; j < 4; j++) {
    int brow = br_base + j * 16;
    bgp[j] = &Wt[(size_t)brow * IN_FEAT + ((bc ^ (brow & 3)) << 3)];
  }

  f32x4 acc[4][4];
#pragma unroll
  for (int mi = 0; mi < 4; mi++)
#pragma unroll
    for (int ni = 0; ni < 4; ni++) acc[mi][ni] = (f32x4){0.f, 0.f, 0.f, 0.f};

  // prologue: stage k0=0 into buffer 0
#pragma unroll
  for (int j = 0; j < 2; j++)
    gl16(agp[j], (char*)AsF + wave * 2048 + j * 1024);
#pragma unroll
  for (int j = 0; j < 4; j++)
    gl16(bgp[j], (char*)BsS + wave * 4096 + j * 1024);

  int cur = 0;
  for (int k0 = 0; k0 < IN_FEAT; k0 += 32) {
    __syncthreads();   // buf[cur] staged (vmcnt drain) + prev compute done

    if (k0 + 32 < IN_FEAT) {
      int nbA = (cur ^ 1) * 8192;
      int nbB = (cur ^ 1) * 16384;
#pragma unroll
      for (int j = 0; j < 2; j++)
        gl16(agp[j] + k0 + 32, (char*)AsF + nbA + wave * 2048 + j * 1024);
#pragma unroll
      for (int j = 0; j < 4; j++)
        gl16(bgp[j] + k0 + 32, (char*)BsS + nbB + wave * 4096 + j * 1024);
    }

    const float* Abuf = AsF + cur * 2048;            // floats
    const unsigned short* Bbuf = BsS + cur * 8192;   // ushorts
    short8x af[4];
#pragma unroll
    for (int mi = 0; mi < 4; mi++) {
      int row = mi * 16 + r;
      int sw = row & 7;
      const float* Ar = &Abuf[row * 32];
      f32x4 a0 = *(const f32x4*)&Ar[(((q << 1)) ^ sw) << 2];
      f32x4 a1 = *(const f32x4*)&Ar[(((q << 1) | 1) ^ sw) << 2];
      short8x a;
      a[0] = (short)f2bf(a0[0]); a[1] = (short)f2bf(a0[1]);
      a[2] = (short)f2bf(a0[2]); a[3] = (short)f2bf(a0[3]);
      a[4] = (short)f2bf(a1[0]); a[5] = (short)f2bf(a1[1]);
      a[6] = (short)f2bf(a1[2]); a[7] = (short)f2bf(a1[3]);
      af[mi] = a;
    }
#pragma unroll
    for (int ni = 0; ni < 4; ni++) {
      int row = wn + ni * 16 + r;
      short8x b = *(const short8x*)&Bbuf[row * 32 + ((q ^ (row & 3)) << 3)];
#pragma unroll
      for (int mi = 0; mi < 4; mi++)
        acc[mi][ni] = __builtin_amdgcn_mfma_f32_16x16x32_bf16(af[mi], b,
                                                              acc[mi][ni], 0, 0, 0);
    }
    cur ^= 1;
  }
#pragma unroll
  for (int mi = 0; mi < 4; mi++) {
#pragma unroll
    for (int ni = 0; ni < 4; ni++) {
      int col = wn + ni * 16 + r;
#pragma unroll
      for (int reg = 0; reg < 4; reg++) {
        int row = m0 + mi * 16 + q * 4 + reg;
        if (row < N_NODES)
          C[(size_t)row * HIDDEN + col] = f2bf(acc[mi][ni][reg]);
      }
    }
  }
}

// ---------------- SpMM1: h = bf16(relu(A @ support1 + b1)) ------------------
// one wave per node; 2 edge-slots x 32 lanes x ushort8 (16 B) per row.
// v5: SINGLE launch (visibility: must appear in top-5 above the ~120 us
// harness fill so we get its FETCH_SIZE -> decides HBM-vs-L3 gather regime).
// nt hints: sedge is streamed once (don't cache), H store bypasses caches --
// preserves L2/L3 residency for the support1 gather target (read ~32x/row).
__global__ __launch_bounds__(256) void k_spmm1(const unsigned short* __restrict__ S,
                                               const int* __restrict__ rptr,
                                               const int2* __restrict__ sedge,
                                               const float* __restrict__ b1,
                                               unsigned short* __restrict__ H) {
  const int node = (blockIdx.x * blockDim.x + threadIdx.x) >> 6;
  const int lane = threadIdx.x & 63;
  const int half = lane >> 5;   // edge slot 0/1
  const int fl = lane & 31;     // feature group: feats fl*8 .. fl*8+7
  int e0 = rptr[node], e1 = rptr[node + 1];
  float a[8];
#pragma unroll
  for (int k = 0; k < 8; k++) a[k] = 0.f;
  for (int base = e0; base < e1; base += 64) {
    int rem = min(64, e1 - base);
    int c = 0;
    float v = 0.f;
    if (lane < rem) {
      long long e = __builtin_nontemporal_load(
          (const long long*)&sedge[base + lane]);
      c = (int)e;
      v = __int_as_float((int)(e >> 32));
    }
    int iters = (rem + 1) >> 1;
#pragma unroll 8
    for (int j = 0; j < iters; j++) {
      int idx = 2 * j + half;            // inactive tail: c=0,v=0 -> adds 0
      int cj = __shfl(c, idx);
      float vj = __shfl(v, idx);
      short8x s8 = *(const short8x*)&S[(size_t)cj * HIDDEN + fl * 8];
#pragma unroll
      for (int k = 0; k < 8; k++)
        a[k] += vj * bf2f((unsigned short)s8[k]);
    }
  }
#pragma unroll
  for (int k = 0; k < 8; k++) a[k] += __shfl_xor(a[k], 32);
  if (half == 0) {
    float4 b0 = *(const float4*)&b1[fl * 8];
    float4 b4 = *(const float4*)&b1[fl * 8 + 4];
    u16x8 o;
    o[0] = f2bf(fmaxf(a[0] + b0.x, 0.f));
    o[1] = f2bf(fmaxf(a[1] + b0.y, 0.f));
    o[2] = f2bf(fmaxf(a[2] + b0.z, 0.f));
    o[3] = f2bf(fmaxf(a[3] + b0.w, 0.f));
    o[4] = f2bf(fmaxf(a[4] + b4.x, 0.f));
    o[5] = f2bf(fmaxf(a[5] + b4.y, 0.f));
    o[6] = f2bf(fmaxf(a[6] + b4.z, 0.f));
    o[7] = f2bf(fmaxf(a[7] + b4.w, 0.f));
    __builtin_nontemporal_store(o, (u16x8*)&H[(size_t)node * HIDDEN + fl * 8]);
  }
}

// ------- GEMM2 (MFMA): support2 = bf16(H @ W2t^T), 48-col, K=256 ------------
__global__ __launch_bounds__(256) void k_gemm2(const unsigned short* __restrict__ H,
                                               const unsigned short* __restrict__ W2t,
                                               unsigned short* __restrict__ S2) {
  const int t = threadIdx.x;
  const int wave = t >> 6, lane = t & 63;
  const int q = lane >> 4, r = lane & 15;
  const int m0 = blockIdx.x * 64 + wave * 16;

  f32x4 acc[3];
#pragma unroll
  for (int n = 0; n < 3; n++) acc[n] = (f32x4){0.f, 0.f, 0.f, 0.f};

  int arow = m0 + r;
  if (arow > N_NODES - 1) arow = N_NODES - 1;
  const unsigned short* Arow = &H[(size_t)arow * HIDDEN + q * 8];

#pragma unroll
  for (int k0 = 0; k0 < HIDDEN; k0 += 32) {
    short8x af = *(const short8x*)&Arow[k0];
    short8x bf0 = *(const short8x*)&W2t[(0 * 16 + r) * HIDDEN + k0 + q * 8];
    short8x bf1 = *(const short8x*)&W2t[(1 * 16 + r) * HIDDEN + k0 + q * 8];
    short8x bf2 = *(const short8x*)&W2t[(2 * 16 + r) * HIDDEN + k0 + q * 8];
    acc[0] = __builtin_amdgcn_mfma_f32_16x16x32_bf16(af, bf0, acc[0], 0, 0, 0);
    acc[1] = __builtin_amdgcn_mfma_f32_16x16x32_bf16(af, bf1, acc[1], 0, 0, 0);
    acc[2] = __builtin_amdgcn_mfma_f32_16x16x32_bf16(af, bf2, acc[2], 0, 0, 0);
  }
  // C layout: col = r, row = q*4+reg
#pragma unroll
  for (int n = 0; n < 3; n++) {
#pragma unroll
    for (int reg = 0; reg < 4; reg++) {
      int row = m0 + q * 4 + reg;
      if (row < N_NODES)
        S2[(size_t)row * S2_STRIDE + n * 16 + r] = f2bf(acc[n][reg]);
    }
  }
}

// --- SpMM2 + bias + log_softmax: 8 edge-slots x 8 lanes x 6 bf16 (12 B) -----
// v5: nt load for sedge (streamed), nt store for out (write-once) --
// preserves cache residency for support2 gathers.
__global__ __launch_bounds__(256) void k_spmm2(const unsigned short* __restrict__ S2,
                                               const int* __restrict__ rptr,
                                               const int2* __restrict__ sedge,
                                               const float* __restrict__ b2,
                                               float* __restrict__ out) {
  const int node = (blockIdx.x * blockDim.x + threadIdx.x) >> 6;
  const int lane = threadIdx.x & 63;
  const int q = lane >> 3;    // edge slot 0..7
  const int fl = lane & 7;    // feats fl*6 .. fl*6+5 (covers 0..47 incl pad)
  int e0 = rptr[node], e1 = rptr[node + 1];
  float a[6] = {0.f, 0.f, 0.f, 0.f, 0.f, 0.f};
  for (int base = e0; base < e1; base += 64) {
    int rem = min(64, e1 - base);
    int c = 0;
    float v = 0.f;
    if (lane < rem) {
      long long e = __builtin_nontemporal_load(
          (const long long*)&sedge[base + lane]);
      c = (int)e;
      v = __int_as_float((int)(e >> 32));
    }
    int iters = (rem + 7) >> 3;
#pragma unroll 8
    for (int j = 0; j < iters; j++) {
      int idx = 8 * j + q;               // inactive tail: c=0,v=0 -> adds 0
      int cj = __shfl(c, idx);
      float vj = __shfl(v, idx);
      u32x3 w = *(const u32x3*)&S2[(size_t)cj * S2_STRIDE + fl * 6];
      a[0] += vj * bflo(w.x);
      a[1] += vj * bfhi(w.x);
      a[2] += vj * bflo(w.y);
      a[3] += vj * bfhi(w.y);
      a[4] += vj * bflo(w.z);
      a[5] += vj * bfhi(w.z);
    }
  }
#pragma unroll
  for (int k = 0; k < 6; k++) {
    a[k] += __shfl_xor(a[k], 8);
    a[k] += __shfl_xor(a[k], 16);
    a[k] += __shfl_xor(a[k], 32);
  }
  float x[6];
  float mloc = -INFINITY;
#pragma unroll
  for (int k = 0; k < 6; k++) {
    int f = fl * 6 + k;
    x[k] = (f < N_CLASS) ? (a[k] + b2[f]) : -INFINITY;
    mloc = fmaxf(mloc, x[k]);
  }
#pragma unroll
  for (int o = 1; o < 8; o <<= 1) mloc = fmaxf(mloc, __shfl_xor(mloc, o));
  float sloc = 0.f;
#pragma unroll
  for (int k = 0; k < 6; k++)
    sloc += (fl * 6 + k < N_CLASS) ? expf(x[k] - mloc) : 0.f;
#pragma unroll
  for (int o = 1; o < 8; o <<= 1) sloc += __shfl_xor(sloc, o);
  float ls = logf(sloc);
  if (q == 0) {
#pragma unroll
    for (int k = 0; k < 6; k++) {
      int f = fl * 6 + k;
      if (f < N_CLASS)
        __builtin_nontemporal_store((x[k] - mloc) - ls,
                                    &out[(size_t)node * N_CLASS + f]);
    }
  }
}

// ---------------------------------------------------------------------------
extern "C" void kernel_launch(void* const* d_in, const int* in_sizes, int n_in,
                              void* d_out, int out_size, void* d_ws, size_t ws_size,
                              hipStream_t stream) {
  const float* x    = (const float*)d_in[0];
  const float* w1   = (const float*)d_in[1];
  const float* b1   = (const float*)d_in[2];
  const float* w2   = (const float*)d_in[3];
  const float* b2   = (const float*)d_in[4];
  const float* eval = (const float*)d_in[5];
  const int*   erow = (const int*)d_in[6];
  const int*   ecol = (const int*)d_in[7];
  float* out = (float*)d_out;

  char* ws = (char*)d_ws;
  unsigned short* support1 = (unsigned short*)(ws + OFF_SUPPORT1);
  unsigned short* h        = (unsigned short*)(ws + OFF_H);
  unsigned short* support2 = (unsigned short*)(ws + OFF_SUPPORT2);
  unsigned short* w1t = (unsigned short*)(ws + OFF_W1T);
  unsigned short* w2t = (unsigned short*)(ws + OFF_W2T);
  int*   rptr   = (int*)(ws + OFF_RPTR);
  int*   bcnt   = (int*)(ws + OFF_BCNT);
  int*   bbase  = (int*)(ws + OFF_BBASE);
  int*   bcur   = (int*)(ws + OFF_BCUR);
  int2*  binned = (int2*)(ws + OFF_BINNED);
  int2*  sedge  = (int2*)(ws + OFF_SEDGE);

  // ---- CSR build (bucketed) + weight prep ----
  hipMemsetAsync(bcnt, 0, N_BUCKETS * 4, stream);
  k_bincnt<<<512, 256, 0, stream>>>(erow, bcnt, w1, w1t, w2, w2t);
  k_binscan<<<1, 256, 0, stream>>>(bcnt, bbase, bcur, rptr);
  k_binscatter<<<N_SC_BLOCKS, 256, 0, stream>>>(erow, ecol, eval, bcur, binned);
  k_bucket_csr<<<N_BUCKETS, 256, 0, stream>>>(binned, bbase, rptr, sedge);

  // ---- layer 1 ----
  k_gemm1<<<dim3((N_NODES + 63) / 64, 1), 256, 0, stream>>>(x, w1t, support1);
  k_spmm1<<<N_NODES / 4, 256, 0, stream>>>(support1, rptr, sedge, b1, h);

  // ---- layer 2 ----
  k_gemm2<<<(N_NODES + 63) / 64, 256, 0, stream>>>(h, w2t, support2);
  k_spmm2<<<N_NODES / 4, 256, 0, stream>>>(support2, rptr, sedge, b2, out);
}

// Round 5
// 776.027 us; speedup vs baseline: 1.0389x; 1.0023x over previous
//
#include <hip/hip_runtime.h>
#include <cstdint>
#include <cstddef>

#define N_NODES 100000
#define N_EDGES 3200000
#define IN_FEAT 512
#define HIDDEN  256
#define N_CLASS 40
#define S2_STRIDE 48         // support2 rows padded 40 -> 48 bf16 (96 B)

#define N_BUCKETS 196        // ceil(100000 / 512), bucket = row >> 9
#define SC_CHUNK 4096        // edges per binscatter block (256 thr x 16)
#define N_SC_BLOCKS 782      // ceil(3.2e6 / 4096)

// ---------------------------------------------------------------------------
// Workspace layout (bytes), 256B-aligned
// ---------------------------------------------------------------------------
#define OFF_SUPPORT1 ((size_t)0)
#define OFF_H        ((size_t)51200000)
#define OFF_SUPPORT2 ((size_t)102400000)
#define OFF_W1T      ((size_t)112000000)
#define OFF_W2T      ((size_t)112262144)
#define OFF_RPTR     ((size_t)112286976)
#define OFF_BCNT     ((size_t)112687104)
#define OFF_BBASE    ((size_t)112688128)
#define OFF_BCUR     ((size_t)112689152)
#define OFF_BINNED   ((size_t)112690176)
#define OFF_SEDGE    ((size_t)138290176)

typedef __attribute__((ext_vector_type(8))) short short8x;
typedef __attribute__((ext_vector_type(4))) float f32x4;
typedef __attribute__((ext_vector_type(8))) unsigned short u16x8;
typedef __attribute__((ext_vector_type(3))) unsigned int u32x3;
typedef __attribute__((ext_vector_type(4))) unsigned int u32x4;

static __device__ __forceinline__ unsigned short f2bf(float f) {
  unsigned u = __float_as_uint(f);
  unsigned r = (u + 0x7FFFu + ((u >> 16) & 1u)) >> 16;  // RNE
  return (unsigned short)r;
}
static __device__ __forceinline__ float bf2f(unsigned short s) {
  return __uint_as_float(((unsigned)s) << 16);
}
static __device__ __forceinline__ float bflo(unsigned u) {
  return __uint_as_float(u << 16);
}
static __device__ __forceinline__ float bfhi(unsigned u) {
  return __uint_as_float(u & 0xFFFF0000u);
}

// async global->LDS, 16B per lane, dest = wave-uniform base + lane*16
static __device__ __forceinline__ void gl16(const void* g, void* l) {
  __builtin_amdgcn_global_load_lds(
      (const __attribute__((address_space(1))) unsigned int*)g,
      (__attribute__((address_space(3))) unsigned int*)l, 16, 0, 0);
}

// ------- bucket histogram + W1/W2 transpose/cast (merged, spare threads) ----
// grid 512 x 256 = 131072 threads: covers w1t (131072 elems) and w2t (12288)
__global__ __launch_bounds__(256) void k_bincnt(const int* __restrict__ erow,
                                                int* __restrict__ bcnt,
                                                const float* __restrict__ W1,
                                                unsigned short* __restrict__ W1t,
                                                const float* __restrict__ W2,
                                                unsigned short* __restrict__ W2t) {
  int tid = blockIdx.x * 256 + threadIdx.x;
  {
    int n = tid & 255;
    int k = tid >> 8;
    W1t[(size_t)n * IN_FEAT + k] = f2bf(W1[(size_t)k * HIDDEN + n]);
  }
  if (tid < 48 * HIDDEN) {
    int n = tid >> 8;          // 0..47
    int k = tid & 255;         // 0..255
    W2t[n * HIDDEN + k] = (n < N_CLASS) ? f2bf(W2[(size_t)k * N_CLASS + n]) : 0;
  }
  __shared__ int lh[256];
  lh[threadIdx.x] = 0;
  __syncthreads();
  int i = tid;
  int stride = gridDim.x * blockDim.x;
  for (; i < N_EDGES; i += stride) atomicAdd(&lh[erow[i] >> 9], 1);
  __syncthreads();
  if (threadIdx.x < N_BUCKETS) atomicAdd(&bcnt[threadIdx.x], lh[threadIdx.x]);
}

__global__ __launch_bounds__(256) void k_binscan(const int* __restrict__ bcnt,
                                                 int* __restrict__ bbase,
                                                 int* __restrict__ bcur,
                                                 int* __restrict__ rptr) {
  __shared__ int s[256];
  int t = threadIdx.x;
  int v = (t < N_BUCKETS) ? bcnt[t] : 0;
  s[t] = v;
  __syncthreads();
  for (int off = 1; off < 256; off <<= 1) {
    int y = (t >= off) ? s[t - off] : 0;
    __syncthreads();
    s[t] += y;
    __syncthreads();
  }
  if (t < N_BUCKETS) {
    int e = s[t] - v;
    bbase[t] = e;
    bcur[t] = e;
  }
  if (t == 0) {
    bbase[N_BUCKETS] = N_EDGES;
    rptr[N_NODES] = N_EDGES;
  }
}

__global__ __launch_bounds__(256) void k_binscatter(const int* __restrict__ erow,
                                                    const int* __restrict__ ecol,
                                                    const float* __restrict__ eval,
                                                    int* __restrict__ bcur,
                                                    int2* __restrict__ binned) {
  __shared__ int lcnt[256];
  __shared__ int lcur[256];
  const int t = threadIdx.x;
  const int base = blockIdx.x * SC_CHUNK;
  lcnt[t] = 0;
  __syncthreads();
  int rows[16], cols[16], vals[16];
#pragma unroll
  for (int e = 0; e < 16; e++) {
    int i = base + t + e * 256;
    if (i < N_EDGES) {
      rows[e] = erow[i];
      cols[e] = ecol[i];
      vals[e] = __float_as_int(eval[i]);
      atomicAdd(&lcnt[rows[e] >> 9], 1);
    } else {
      rows[e] = -1;
    }
  }
  __syncthreads();
  if (t < N_BUCKETS) lcur[t] = atomicAdd(&bcur[t], lcnt[t]);
  __syncthreads();
#pragma unroll
  for (int e = 0; e < 16; e++) {
    if (rows[e] >= 0) {
      int bkt = rows[e] >> 9;
      int p = atomicAdd(&lcur[bkt], 1);
      binned[p] = make_int2(((rows[e] & 511) << 17) | cols[e], vals[e]);
    }
  }
}

__global__ __launch_bounds__(256) void k_bucket_csr(const int2* __restrict__ binned,
                                                    const int* __restrict__ bbase,
                                                    int* __restrict__ rptr,
                                                    int2* __restrict__ sedge) {
  const int b = blockIdx.x;
  const int t = threadIdx.x;
  __shared__ int cnt[512];
  __shared__ int excl[512];
  __shared__ int s[256];
  cnt[t] = 0;
  cnt[t + 256] = 0;
  __syncthreads();
  const int ebase = bbase[b];
  const int ecnt = bbase[b + 1] - ebase;
  for (int i = t; i < ecnt; i += 256)
    atomicAdd(&cnt[((unsigned)binned[ebase + i].x) >> 17], 1);
  __syncthreads();
  int c0 = cnt[2 * t], c1 = cnt[2 * t + 1];
  s[t] = c0 + c1;
  __syncthreads();
  for (int off = 1; off < 256; off <<= 1) {
    int y = (t >= off) ? s[t - off] : 0;
    __syncthreads();
    s[t] += y;
    __syncthreads();
  }
  int e = s[t] - (c0 + c1);
  excl[2 * t] = e;
  excl[2 * t + 1] = e + c0;
  __syncthreads();
  for (int i = t; i < 512; i += 256) {
    int node = b * 512 + i;
    if (node < N_NODES) rptr[node] = ebase + excl[i];
  }
  __syncthreads();
  for (int i = t; i < ecnt; i += 256) {
    int2 e2 = binned[ebase + i];
    int lrow = ((unsigned)e2.x) >> 17;
    int col = e2.x & 0x1FFFF;
    int p = atomicAdd(&excl[lrow], 1);
    sedge[ebase + p] = make_int2(col, e2.y);
  }
}

// ------------- GEMM1 (MFMA): support1 = bf16(X @ W1), row-major out ---------
// M=100000, N=256 (full width per block -> X read ONCE), K=512.
// v4 (kept): 64x256 block tile, acc[4][4]=64 acc regs -> 2 waves/SIMD;
// LDS dbuf, gl16 staging, source-swizzle. ~110 us (out of top-5).
__global__ __launch_bounds__(256, 2) void k_gemm1(const float* __restrict__ X,
                                                  const unsigned short* __restrict__ Wt,
                                                  unsigned short* __restrict__ C) {
  __shared__ float AsF[2 * 64 * 32];            // 2 x 8 KB fp32, chunk-swizzled
  __shared__ unsigned short BsS[2 * 256 * 32];  // 2 x 16 KB bf16, chunk-swizzled
  const int t = threadIdx.x;
  const int wave = t >> 6, lane = t & 63;
  const int q = lane >> 4, r = lane & 15;
  const int wn = wave * 64;          // wave's N-offset (0/64/128/192)
  const int m0 = blockIdx.x * 64;

  const int ar_base = wave * 16 + (lane >> 3);
  const int ac = lane & 7;
  const int br_base = wave * 64 + (lane >> 2);
  const int bc = lane & 3;

  const float* agp[2];
  const unsigned short* bgp[4];
#pragma unroll
  for (int j = 0; j < 2; j++) {
    int row = ar_base + j * 8;
    int gr = m0 + row;
    if (gr > N_NODES - 1) gr = N_NODES - 1;
    agp[j] = &X[(size_t)gr * IN_FEAT + ((ac ^ (row & 7)) << 2)];
  }
#pragma unroll
  for (int j = 0; j < 4; j++) {
    int brow = br_base + j * 16;
    bgp[j] = &Wt[(size_t)brow * IN_FEAT + ((bc ^ (brow & 3)) << 3)];
  }

  f32x4 acc[4][4];
#pragma unroll
  for (int mi = 0; mi < 4; mi++)
#pragma unroll
    for (int ni = 0; ni < 4; ni++) acc[mi][ni] = (f32x4){0.f, 0.f, 0.f, 0.f};

  // prologue: stage k0=0 into buffer 0
#pragma unroll
  for (int j = 0; j < 2; j++)
    gl16(agp[j], (char*)AsF + wave * 2048 + j * 1024);
#pragma unroll
  for (int j = 0; j < 4; j++)
    gl16(bgp[j], (char*)BsS + wave * 4096 + j * 1024);

  int cur = 0;
  for (int k0 = 0; k0 < IN_FEAT; k0 += 32) {
    __syncthreads();   // buf[cur] staged (vmcnt drain) + prev compute done

    if (k0 + 32 < IN_FEAT) {
      int nbA = (cur ^ 1) * 8192;
      int nbB = (cur ^ 1) * 16384;
#pragma unroll
      for (int j = 0; j < 2; j++)
        gl16(agp[j] + k0 + 32, (char*)AsF + nbA + wave * 2048 + j * 1024);
#pragma unroll
      for (int j = 0; j < 4; j++)
        gl16(bgp[j] + k0 + 32, (char*)BsS + nbB + wave * 4096 + j * 1024);
    }

    const float* Abuf = AsF + cur * 2048;            // floats
    const unsigned short* Bbuf = BsS + cur * 8192;   // ushorts
    short8x af[4];
#pragma unroll
    for (int mi = 0; mi < 4; mi++) {
      int row = mi * 16 + r;
      int sw = row & 7;
      const float* Ar = &Abuf[row * 32];
      f32x4 a0 = *(const f32x4*)&Ar[(((q << 1)) ^ sw) << 2];
      f32x4 a1 = *(const f32x4*)&Ar[(((q << 1) | 1) ^ sw) << 2];
      short8x a;
      a[0] = (short)f2bf(a0[0]); a[1] = (short)f2bf(a0[1]);
      a[2] = (short)f2bf(a0[2]); a[3] = (short)f2bf(a0[3]);
      a[4] = (short)f2bf(a1[0]); a[5] = (short)f2bf(a1[1]);
      a[6] = (short)f2bf(a1[2]); a[7] = (short)f2bf(a1[3]);
      af[mi] = a;
    }
#pragma unroll
    for (int ni = 0; ni < 4; ni++) {
      int row = wn + ni * 16 + r;
      short8x b = *(const short8x*)&Bbuf[row * 32 + ((q ^ (row & 3)) << 3)];
#pragma unroll
      for (int mi = 0; mi < 4; mi++)
        acc[mi][ni] = __builtin_amdgcn_mfma_f32_16x16x32_bf16(af[mi], b,
                                                              acc[mi][ni], 0, 0, 0);
    }
    cur ^= 1;
  }
#pragma unroll
  for (int mi = 0; mi < 4; mi++) {
#pragma unroll
    for (int ni = 0; ni < 4; ni++) {
      int col = wn + ni * 16 + r;
#pragma unroll
      for (int reg = 0; reg < 4; reg++) {
        int row = m0 + mi * 16 + q * 4 + reg;
        if (row < N_NODES)
          C[(size_t)row * HIDDEN + col] = f2bf(acc[mi][ni][reg]);
      }
    }
  }
}

// ---------------- SpMM1: h = bf16(relu(A @ support1 + b1)) ------------------
// v6: FEATURE-BLOCKED, 2 sequential passes (fo = 0, 128). Round-4 counters:
// FETCH 751 MB vs 77 MB unique -> L3 captured only ~55% of the 1.64 GB gather
// demand (51 MB working set too big under 256-CU random hammering + streams).
// Per pass the gather target is 25.6 MB -> should be L3-resident.
// Wave layout: 4 edge-slots x 16 feat-lanes x 8 feats (row-half 256 B,
// 16 lanes x 16 B coalesced). Results bit-identical (disjoint feat ranges).
__global__ __launch_bounds__(256) void k_spmm1(const unsigned short* __restrict__ S,
                                               const int* __restrict__ rptr,
                                               const int2* __restrict__ sedge,
                                               const float* __restrict__ b1,
                                               unsigned short* __restrict__ H,
                                               int fo) {
  const int node = (blockIdx.x * blockDim.x + threadIdx.x) >> 6;
  const int lane = threadIdx.x & 63;
  const int slot = lane >> 4;   // edge slot 0..3
  const int fl = lane & 15;     // feature group: feats fo+fl*8 .. fo+fl*8+7
  int e0 = rptr[node], e1 = rptr[node + 1];
  float a[8];
#pragma unroll
  for (int k = 0; k < 8; k++) a[k] = 0.f;
  for (int base = e0; base < e1; base += 64) {
    int rem = min(64, e1 - base);
    int c = 0;
    float v = 0.f;
    if (lane < rem) {
      long long e = __builtin_nontemporal_load(
          (const long long*)&sedge[base + lane]);
      c = (int)e;
      v = __int_as_float((int)(e >> 32));
    }
    int iters = (rem + 3) >> 2;
#pragma unroll 8
    for (int j = 0; j < iters; j++) {
      int idx = 4 * j + slot;            // inactive tail: c=0,v=0 -> adds 0
      int cj = __shfl(c, idx);
      float vj = __shfl(v, idx);
      short8x s8 = *(const short8x*)&S[(size_t)cj * HIDDEN + fo + fl * 8];
#pragma unroll
      for (int k = 0; k < 8; k++)
        a[k] += vj * bf2f((unsigned short)s8[k]);
    }
  }
#pragma unroll
  for (int k = 0; k < 8; k++) {
    a[k] += __shfl_xor(a[k], 16);
    a[k] += __shfl_xor(a[k], 32);
  }
  if (slot == 0) {
    float4 b0 = *(const float4*)&b1[fo + fl * 8];
    float4 b4 = *(const float4*)&b1[fo + fl * 8 + 4];
    u16x8 o;
    o[0] = f2bf(fmaxf(a[0] + b0.x, 0.f));
    o[1] = f2bf(fmaxf(a[1] + b0.y, 0.f));
    o[2] = f2bf(fmaxf(a[2] + b0.z, 0.f));
    o[3] = f2bf(fmaxf(a[3] + b0.w, 0.f));
    o[4] = f2bf(fmaxf(a[4] + b4.x, 0.f));
    o[5] = f2bf(fmaxf(a[5] + b4.y, 0.f));
    o[6] = f2bf(fmaxf(a[6] + b4.z, 0.f));
    o[7] = f2bf(fmaxf(a[7] + b4.w, 0.f));
    __builtin_nontemporal_store(
        o, (u16x8*)&H[(size_t)node * HIDDEN + fo + fl * 8]);
  }
}

// ------- GEMM2 (MFMA): support2 = bf16(H @ W2t^T), 48-col, K=256 ------------
__global__ __launch_bounds__(256) void k_gemm2(const unsigned short* __restrict__ H,
                                               const unsigned short* __restrict__ W2t,
                                               unsigned short* __restrict__ S2) {
  const int t = threadIdx.x;
  const int wave = t >> 6, lane = t & 63;
  const int q = lane >> 4, r = lane & 15;
  const int m0 = blockIdx.x * 64 + wave * 16;

  f32x4 acc[3];
#pragma unroll
  for (int n = 0; n < 3; n++) acc[n] = (f32x4){0.f, 0.f, 0.f, 0.f};

  int arow = m0 + r;
  if (arow > N_NODES - 1) arow = N_NODES - 1;
  const unsigned short* Arow = &H[(size_t)arow * HIDDEN + q * 8];

#pragma unroll
  for (int k0 = 0; k0 < HIDDEN; k0 += 32) {
    short8x af = *(const short8x*)&Arow[k0];
    short8x bf0 = *(const short8x*)&W2t[(0 * 16 + r) * HIDDEN + k0 + q * 8];
    short8x bf1 = *(const short8x*)&W2t[(1 * 16 + r) * HIDDEN + k0 + q * 8];
    short8x bf2 = *(const short8x*)&W2t[(2 * 16 + r) * HIDDEN + k0 + q * 8];
    acc[0] = __builtin_amdgcn_mfma_f32_16x16x32_bf16(af, bf0, acc[0], 0, 0, 0);
    acc[1] = __builtin_amdgcn_mfma_f32_16x16x32_bf16(af, bf1, acc[1], 0, 0, 0);
    acc[2] = __builtin_amdgcn_mfma_f32_16x16x32_bf16(af, bf2, acc[2], 0, 0, 0);
  }
  // C layout: col = r, row = q*4+reg
#pragma unroll
  for (int n = 0; n < 3; n++) {
#pragma unroll
    for (int reg = 0; reg < 4; reg++) {
      int row = m0 + q * 4 + reg;
      if (row < N_NODES)
        S2[(size_t)row * S2_STRIDE + n * 16 + r] = f2bf(acc[n][reg]);
    }
  }
}

// --- SpMM2 + bias + log_softmax: 8 edge-slots x 8 lanes x 6 bf16 (12 B) -----
__global__ __launch_bounds__(256) void k_spmm2(const unsigned short* __restrict__ S2,
                                               const int* __restrict__ rptr,
                                               const int2* __restrict__ sedge,
                                               const float* __restrict__ b2,
                                               float* __restrict__ out) {
  const int node = (blockIdx.x * blockDim.x + threadIdx.x) >> 6;
  const int lane = threadIdx.x & 63;
  const int q = lane >> 3;    // edge slot 0..7
  const int fl = lane & 7;    // feats fl*6 .. fl*6+5 (covers 0..47 incl pad)
  int e0 = rptr[node], e1 = rptr[node + 1];
  float a[6] = {0.f, 0.f, 0.f, 0.f, 0.f, 0.f};
  for (int base = e0; base < e1; base += 64) {
    int rem = min(64, e1 - base);
    int c = 0;
    float v = 0.f;
    if (lane < rem) {
      long long e = __builtin_nontemporal_load(
          (const long long*)&sedge[base + lane]);
      c = (int)e;
      v = __int_as_float((int)(e >> 32));
    }
    int iters = (rem + 7) >> 3;
#pragma unroll 8
    for (int j = 0; j < iters; j++) {
      int idx = 8 * j + q;               // inactive tail: c=0,v=0 -> adds 0
      int cj = __shfl(c, idx);
      float vj = __shfl(v, idx);
      u32x3 w = *(const u32x3*)&S2[(size_t)cj * S2_STRIDE + fl * 6];
      a[0] += vj * bflo(w.x);
      a[1] += vj * bfhi(w.x);
      a[2] += vj * bflo(w.y);
      a[3] += vj * bfhi(w.y);
      a[4] += vj * bflo(w.z);
      a[5] += vj * bfhi(w.z);
    }
  }
#pragma unroll
  for (int k = 0; k < 6; k++) {
    a[k] += __shfl_xor(a[k], 8);
    a[k] += __shfl_xor(a[k], 16);
    a[k] += __shfl_xor(a[k], 32);
  }
  float x[6];
  float mloc = -INFINITY;
#pragma unroll
  for (int k = 0; k < 6; k++) {
    int f = fl * 6 + k;
    x[k] = (f < N_CLASS) ? (a[k] + b2[f]) : -INFINITY;
    mloc = fmaxf(mloc, x[k]);
  }
#pragma unroll
  for (int o = 1; o < 8; o <<= 1) mloc = fmaxf(mloc, __shfl_xor(mloc, o));
  float sloc = 0.f;
#pragma unroll
  for (int k = 0; k < 6; k++)
    sloc += (fl * 6 + k < N_CLASS) ? expf(x[k] - mloc) : 0.f;
#pragma unroll
  for (int o = 1; o < 8; o <<= 1) sloc += __shfl_xor(sloc, o);
  float ls = logf(sloc);
  if (q == 0) {
#pragma unroll
    for (int k = 0; k < 6; k++) {
      int f = fl * 6 + k;
      if (f < N_CLASS)
        __builtin_nontemporal_store((x[k] - mloc) - ls,
                                    &out[(size_t)node * N_CLASS + f]);
    }
  }
}

// ---------------------------------------------------------------------------
extern "C" void kernel_launch(void* const* d_in, const int* in_sizes, int n_in,
                              void* d_out, int out_size, void* d_ws, size_t ws_size,
                              hipStream_t stream) {
  const float* x    = (const float*)d_in[0];
  const float* w1   = (const float*)d_in[1];
  const float* b1   = (const float*)d_in[2];
  const float* w2   = (const float*)d_in[3];
  const float* b2   = (const float*)d_in[4];
  const float* eval = (const float*)d_in[5];
  const int*   erow = (const int*)d_in[6];
  const int*   ecol = (const int*)d_in[7];
  float* out = (float*)d_out;

  char* ws = (char*)d_ws;
  unsigned short* support1 = (unsigned short*)(ws + OFF_SUPPORT1);
  unsigned short* h        = (unsigned short*)(ws + OFF_H);
  unsigned short* support2 = (unsigned short*)(ws + OFF_SUPPORT2);
  unsigned short* w1t = (unsigned short*)(ws + OFF_W1T);
  unsigned short* w2t = (unsigned short*)(ws + OFF_W2T);
  int*   rptr   = (int*)(ws + OFF_RPTR);
  int*   bcnt   = (int*)(ws + OFF_BCNT);
  int*   bbase  = (int*)(ws + OFF_BBASE);
  int*   bcur   = (int*)(ws + OFF_BCUR);
  int2*  binned = (int2*)(ws + OFF_BINNED);
  int2*  sedge  = (int2*)(ws + OFF_SEDGE);

  // ---- CSR build (bucketed) + weight prep ----
  hipMemsetAsync(bcnt, 0, N_BUCKETS * 4, stream);
  k_bincnt<<<512, 256, 0, stream>>>(erow, bcnt, w1, w1t, w2, w2t);
  k_binscan<<<1, 256, 0, stream>>>(bcnt, bbase, bcur, rptr);
  k_binscatter<<<N_SC_BLOCKS, 256, 0, stream>>>(erow, ecol, eval, bcur, binned);
  k_bucket_csr<<<N_BUCKETS, 256, 0, stream>>>(binned, bbase, rptr, sedge);

  // ---- layer 1 ----
  k_gemm1<<<dim3((N_NODES + 63) / 64, 1), 256, 0, stream>>>(x, w1t, support1);
  k_spmm1<<<N_NODES / 4, 256, 0, stream>>>(support1, rptr, sedge, b1, h, 0);
  k_spmm1<<<N_NODES / 4, 256, 0, stream>>>(support1, rptr, sedge, b1, h, 128);

  // ---- layer 2 ----
  k_gemm2<<<(N_NODES + 63) / 64, 256, 0, stream>>>(h, w2t, support2);
  k_spmm2<<<N_NODES / 4, 256, 0, stream>>>(support2, rptr, sedge, b2, out);
}